// Round 4
// baseline (318.670 us; speedup 1.0000x reference)
//
#include <hip/hip_runtime.h>
#include <hip/hip_bf16.h>
#include <stdint.h>

typedef unsigned short u16;
typedef __bf16 bf16x8 __attribute__((ext_vector_type(8)));
typedef float f32x4 __attribute__((ext_vector_type(4)));

#define MTOT 65536

__device__ __forceinline__ u16 f2b(float f) {
    uint32_t u = __float_as_uint(f);
    u += 0x7fffu + ((u >> 16) & 1u);
    return (u16)(u >> 16);
}
__device__ __forceinline__ float b2f(u16 h) {
    return __uint_as_float(((uint32_t)h) << 16);
}

__device__ __forceinline__ void gload16(const void* g, void* l) {
    __builtin_amdgcn_global_load_lds((const __attribute__((address_space(1))) void*)g,
                                     (__attribute__((address_space(3))) void*)l, 16, 0, 0);
}

// stage one 128x32 bf16 tile (64B rows) via global_load_lds, with XOR-swizzled
// SOURCE columns (rule 21: LDS dest linear, source pre-permuted, read applies same XOR).
// content(row, chunk c) lands at LDS byte row*64 + (c ^ (row&3))*16.
__device__ __forceinline__ void stage32(const char* gbase, size_t ldb,
                                        u16* lbuf, int wave, int lane) {
    int sw = ((lane & 3) ^ ((lane >> 2) & 3)) << 4;   // swizzled source chunk
    const char* src = gbase + (size_t)(wave * 32 + (lane >> 2)) * ldb + sw;
    gload16(src, lbuf + (wave * 32) * 32);
    gload16(src + (size_t)16 * ldb, lbuf + (wave * 32 + 16) * 32);
}

// one BK=32 MFMA step; reads apply the same XOR on the 16B chunk index.
__device__ __forceinline__ void compute32(const u16* As, const u16* Ws, int wm, int wn,
                                          int l16, int q, f32x4 (&acc)[4][4]) {
    bf16x8 af[4], wf[4];
    int xo = ((q ^ (l16 & 3)) << 3);   // element offset of swizzled 16B chunk
#pragma unroll
    for (int mi = 0; mi < 4; ++mi)
        af[mi] = *(const bf16x8*)&As[(wm * 64 + mi * 16 + l16) * 32 + xo];
#pragma unroll
    for (int ni = 0; ni < 4; ++ni)
        wf[ni] = *(const bf16x8*)&Ws[(wn * 64 + ni * 16 + l16) * 32 + xo];
#pragma unroll
    for (int mi = 0; mi < 4; ++mi)
#pragma unroll
        for (int ni = 0; ni < 4; ++ni)
            acc[mi][ni] = __builtin_amdgcn_mfma_f32_16x16x32_bf16(af[mi], wf[ni], acc[mi][ni], 0, 0, 0);
}

// XCD-aware bijective swizzle (nwg % 8 == 0 required)
__device__ __forceinline__ int xcd_swz(int flat, int nwg) {
    int chunk = nwg >> 3;
    return (flat & 7) * chunk + (flat >> 3);
}

// ---------------- zero stats ----------------
__global__ void zero_stats(float* __restrict__ p) {
    int i = blockIdx.x * 256 + threadIdx.x;
    if (i < 3072) p[i] = 0.f;
}

// ---------------- PE table: PEC[(dy*8+dx)][n] ----------------
__global__ __launch_bounds__(512) void build_pec(const float* __restrict__ w1,
                                                 const float* __restrict__ b1,
                                                 float* __restrict__ pec) {
    __shared__ float pe[168];
    int dy = blockIdx.x >> 3, dx = blockIdx.x & 7;
    int t = threadIdx.x;
    if (t < 168) {
        int lv = t / 42, j = t - lv * 42;
        int msk = (1 << lv) - 1;
        float inv = 1.0f / (float)(1 << lv);
        float ry = (float)(2 * (dy & msk) + 1) * inv - 1.0f;
        float rx = (float)(2 * (dx & msk) + 1) * inv - 1.0f;
        float v;
        if (j == 0) v = ry;
        else if (j == 1) v = rx;
        else if (j < 12)  v = sinf(exp2f((float)(j - 2)  * (2.0f/3.0f)) * ry);
        else if (j < 22)  v = sinf(exp2f((float)(j - 12) * (2.0f/3.0f)) * rx);
        else if (j < 32)  v = cosf(exp2f((float)(j - 22) * (2.0f/3.0f)) * ry);
        else              v = cosf(exp2f((float)(j - 32) * (2.0f/3.0f)) * rx);
        pe[t] = v;
    }
    __syncthreads();
    int n = t;
    float acc = b1[n];
#pragma unroll 4
    for (int lv = 0; lv < 4; ++lv)
        for (int j = 0; j < 42; ++j)
            acc += pe[lv * 42 + j] * w1[n * 1192 + lv * 298 + j];
    pec[(size_t)blockIdx.x * 512 + n] = acc;
}

// ---------------- W1 feature-part extract ----------------
__global__ void cvt_w1f(const float* __restrict__ w1, u16* __restrict__ dst) {
    for (int i = blockIdx.x * 256 + threadIdx.x; i < 4 * 512 * 256; i += gridDim.x * 256) {
        int lv = i >> 17;
        int rem = i & 131071;
        int n = rem >> 8, c = rem & 255;
        dst[i] = f2b(w1[n * 1192 + lv * 298 + 42 + c]);
    }
}

// ---------------- flat f32 -> bf16 ----------------
__global__ void cvt_flat(const float* __restrict__ src, u16* __restrict__ dst, int total) {
    for (int i = blockIdx.x * 256 + threadIdx.x; i < total; i += gridDim.x * 256)
        dst[i] = f2b(src[i]);
}

// ---------------- transpose+convert x [B][256][plane] f32 -> A [B*plane][256] bf16
__global__ __launch_bounds__(256) void cvt_tr(const float* __restrict__ xs,
                                              u16* __restrict__ A, int shift) {
    __shared__ float sm[64][65];
    int t = threadIdx.x;
    int p0 = blockIdx.x * 64;
    int pix = t & 63, c0 = t >> 6;
    int plane = 1 << shift;
    int gp = p0 + pix;
    int b = gp >> shift;
    int l = gp & (plane - 1);
    const float* src = xs + ((size_t)b * 256) * plane + l;
    for (int cblk = 0; cblk < 4; ++cblk) {
#pragma unroll
        for (int it = 0; it < 16; ++it) {
            int c = it * 4 + c0;
            sm[pix][c] = src[(size_t)(cblk * 64 + c) * plane];
        }
        __syncthreads();
#pragma unroll
        for (int it = 0; it < 2; ++it) {
            int u = it * 256 + t;
            int ml = u >> 3, c8 = u & 7;
            const float* sr = &sm[ml][c8 * 8];
            uint4 v;
            v.x = (uint32_t)f2b(sr[0]) | ((uint32_t)f2b(sr[1]) << 16);
            v.y = (uint32_t)f2b(sr[2]) | ((uint32_t)f2b(sr[3]) << 16);
            v.z = (uint32_t)f2b(sr[4]) | ((uint32_t)f2b(sr[5]) << 16);
            v.w = (uint32_t)f2b(sr[6]) | ((uint32_t)f2b(sr[7]) << 16);
            *(uint4*)&A[(size_t)(p0 + ml) * 256 + cblk * 64 + c8 * 8] = v;
        }
        __syncthreads();
    }
}

// ---------------- pipelined GEMM: Y[m][n] = sum_k Act[m][k]*W[n][k] (+bias)(+stats) ----------------
// 128x128 tile, BK=32 (32KB LDS -> 5 blocks/CU), dbuf + global_load_lds + swizzle.
__global__ __launch_bounds__(256) void gemm_bt(const u16* __restrict__ W,
                                               const u16* __restrict__ Act,
                                               const float* __restrict__ bias,
                                               u16* __restrict__ Y,
                                               float* __restrict__ stats, int N, int K) {
    __shared__ u16 As[2][4096];
    __shared__ u16 Ws[2][4096];
    int tid = threadIdx.x;
    int wave = tid >> 6, lane = tid & 63;
    int wm = wave >> 1, wn = wave & 1;
    int nwg = gridDim.x * gridDim.y;
    int swz = xcd_swz(blockIdx.y * gridDim.x + blockIdx.x, nwg);
    int n0 = (swz % gridDim.x) * 128, m0 = (swz / gridDim.x) * 128;
    int q = lane >> 4, l16 = lane & 15;
    f32x4 acc[4][4];
#pragma unroll
    for (int i = 0; i < 4; ++i)
#pragma unroll
        for (int j = 0; j < 4; ++j) acc[i][j] = {0.f, 0.f, 0.f, 0.f};
    const char* actb = (const char*)Act + (size_t)m0 * K * 2;
    const char* wb = (const char*)W + (size_t)n0 * K * 2;
    size_t ldb = (size_t)K * 2;
    stage32(actb, ldb, As[0], wave, lane);
    stage32(wb, ldb, Ws[0], wave, lane);
    __syncthreads();
    int cur = 0;
    for (int kt = 32; kt < K; kt += 32) {
        stage32(actb + kt * 2, ldb, As[cur ^ 1], wave, lane);
        stage32(wb + kt * 2, ldb, Ws[cur ^ 1], wave, lane);
        compute32(As[cur], Ws[cur], wm, wn, l16, q, acc);
        __syncthreads();
        cur ^= 1;
    }
    compute32(As[cur], Ws[cur], wm, wn, l16, q, acc);

    float bv[4];
#pragma unroll
    for (int ni = 0; ni < 4; ++ni)
        bv[ni] = bias ? bias[n0 + wn * 64 + ni * 16 + l16] : 0.f;
    float s1[4] = {0.f, 0.f, 0.f, 0.f}, s2[4] = {0.f, 0.f, 0.f, 0.f};
#pragma unroll
    for (int mi = 0; mi < 4; ++mi) {
#pragma unroll
        for (int r = 0; r < 4; ++r) {
            int m = m0 + wm * 64 + mi * 16 + q * 4 + r;
#pragma unroll
            for (int ni = 0; ni < 4; ++ni) {
                float v = acc[mi][ni][r] + bv[ni];
                Y[(size_t)m * N + (n0 + wn * 64 + ni * 16 + l16)] = f2b(v);
                s1[ni] += v;
                s2[ni] += v * v;
            }
        }
    }
    if (stats) {
#pragma unroll
        for (int ni = 0; ni < 4; ++ni) {
            float a = s1[ni], bq = s2[ni];
            a += __shfl_xor(a, 16); a += __shfl_xor(a, 32);
            bq += __shfl_xor(bq, 16); bq += __shfl_xor(bq, 32);
            if (q == 0) {
                int n = n0 + wn * 64 + ni * 16 + l16;
                atomicAdd(&stats[n], a);
                atomicAdd(&stats[N + n], bq);
            }
        }
    }
}

// ---------------- merged low-res level GEMMs: G_lv = A_lv * W_lv^T ----------------
// grid (4, 168): y<128 -> lv1 (16384 rows), y<160 -> lv2 (4096), else lv3 (1024)
__global__ __launch_bounds__(256) void gemm_levels(const u16* __restrict__ wb1f,
                                                   const u16* __restrict__ A1,
                                                   const u16* __restrict__ A2,
                                                   const u16* __restrict__ A3,
                                                   u16* __restrict__ G1,
                                                   u16* __restrict__ G2,
                                                   u16* __restrict__ G3) {
    __shared__ u16 As[2][4096];
    __shared__ u16 Ws[2][4096];
    int tid = threadIdx.x;
    int wave = tid >> 6, lane = tid & 63;
    int wm = wave >> 1, wn = wave & 1;
    int swz = xcd_swz(blockIdx.y * 4 + blockIdx.x, 672);
    int bx = swz & 3, by = swz >> 2;
    const u16* A; u16* G; const u16* W;
    int mt;
    if (by < 128)      { A = A1; G = G1; W = wb1f + 1 * 131072; mt = by; }
    else if (by < 160) { A = A2; G = G2; W = wb1f + 2 * 131072; mt = by - 128; }
    else               { A = A3; G = G3; W = wb1f + 3 * 131072; mt = by - 160; }
    int n0 = bx * 128, m0 = mt * 128;
    int q = lane >> 4, l16 = lane & 15;
    f32x4 acc[4][4];
#pragma unroll
    for (int i = 0; i < 4; ++i)
#pragma unroll
        for (int j = 0; j < 4; ++j) acc[i][j] = {0.f, 0.f, 0.f, 0.f};
    const char* actb = (const char*)A + (size_t)m0 * 512;
    const char* wb = (const char*)W + (size_t)n0 * 512;
    stage32(actb, 512, As[0], wave, lane);
    stage32(wb, 512, Ws[0], wave, lane);
    __syncthreads();
    int cur = 0;
#pragma unroll
    for (int kt = 0; kt < 8; ++kt) {
        if (kt < 7) {
            stage32(actb + (kt + 1) * 64, 512, As[cur ^ 1], wave, lane);
            stage32(wb + (kt + 1) * 64, 512, Ws[cur ^ 1], wave, lane);
        }
        compute32(As[cur], Ws[cur], wm, wn, l16, q, acc);
        __syncthreads();
        cur ^= 1;
    }
#pragma unroll
    for (int mi = 0; mi < 4; ++mi)
#pragma unroll
        for (int r = 0; r < 4; ++r) {
            int m = m0 + wm * 64 + mi * 16 + q * 4 + r;
#pragma unroll
            for (int ni = 0; ni < 4; ++ni)
                G[(size_t)m * 512 + (n0 + wn * 64 + ni * 16 + l16)] = f2b(acc[mi][ni][r]);
        }
}

// ---------------- fused layer-1 GEMM + gathers + PEC + stats ----------------
// grid (4, 512). m-tile of 128 = one (b, iy) row, ix 0..127. K=256.
__global__ __launch_bounds__(256) void gemm_f1(const u16* __restrict__ W,
                                               const u16* __restrict__ A0,
                                               const u16* __restrict__ G1,
                                               const u16* __restrict__ G2,
                                               const u16* __restrict__ G3,
                                               const float* __restrict__ pec,
                                               u16* __restrict__ Y,
                                               float* __restrict__ stats) {
    __shared__ u16 As[2][4096];
    __shared__ u16 Ws[2][4096];
    int tid = threadIdx.x;
    int wave = tid >> 6, lane = tid & 63;
    int wm = wave >> 1, wn = wave & 1;
    int swz = xcd_swz(blockIdx.y * 4 + blockIdx.x, 2048);
    int n0 = (swz & 3) * 128, m0 = (swz >> 2) * 128;
    int q = lane >> 4, l16 = lane & 15;
    f32x4 acc[4][4];
#pragma unroll
    for (int i = 0; i < 4; ++i)
#pragma unroll
        for (int j = 0; j < 4; ++j) acc[i][j] = {0.f, 0.f, 0.f, 0.f};
    const char* actb = (const char*)A0 + (size_t)m0 * 512;
    const char* wb = (const char*)W + (size_t)n0 * 512;
    stage32(actb, 512, As[0], wave, lane);
    stage32(wb, 512, Ws[0], wave, lane);
    __syncthreads();
    int cur = 0;
#pragma unroll
    for (int kt = 0; kt < 8; ++kt) {
        if (kt < 7) {
            stage32(actb + (kt + 1) * 64, 512, As[cur ^ 1], wave, lane);
            stage32(wb + (kt + 1) * 64, 512, Ws[cur ^ 1], wave, lane);
        }
        compute32(As[cur], Ws[cur], wm, wn, l16, q, acc);
        __syncthreads();
        cur ^= 1;
    }
    // ---- epilogue: stage gather rows in LDS (reuses As/Ws; barrier above protects) ----
    u16* g1s = &As[0][0];                    // [64][128] 16KB (spans both buffers)
    u16* g2s = &Ws[0][0];                    // [32][128] 8KB
    u16* g3s = &Ws[0][0] + 4096;             // [16][128] 4KB
    float* pecs = (float*)(&Ws[0][0] + 6144);// [8][128] 4KB
    int b = m0 >> 14;
    int iy = (m0 >> 7) & 127;
    {
        const u16* g1p = G1 + ((size_t)(b * 4096 + (iy >> 1) * 64)) * 512 + n0;
#pragma unroll
        for (int it = 0; it < 4; ++it) {
            int u = it * 256 + tid;
            int row = u >> 4, c8 = u & 15;
            *(uint4*)&g1s[row * 128 + c8 * 8] = *(const uint4*)&g1p[(size_t)row * 512 + c8 * 8];
        }
        const u16* g2p = G2 + ((size_t)(b * 1024 + (iy >> 2) * 32)) * 512 + n0;
#pragma unroll
        for (int it = 0; it < 2; ++it) {
            int u = it * 256 + tid;
            int row = u >> 4, c8 = u & 15;
            *(uint4*)&g2s[row * 128 + c8 * 8] = *(const uint4*)&g2p[(size_t)row * 512 + c8 * 8];
        }
        const u16* g3p = G3 + ((size_t)(b * 256 + (iy >> 3) * 16)) * 512 + n0;
        {
            int row = tid >> 4, c8 = tid & 15;
            *(uint4*)&g3s[row * 128 + c8 * 8] = *(const uint4*)&g3p[(size_t)row * 512 + c8 * 8];
        }
        const float* pp = pec + (size_t)((iy & 7) * 8) * 512 + n0;
        {
            int row = tid >> 5, c4 = tid & 31;
            *(uint4*)&pecs[row * 128 + c4 * 4] = *(const uint4*)&pp[(size_t)row * 512 + c4 * 4];
        }
    }
    __syncthreads();
    float s1[4] = {0.f, 0.f, 0.f, 0.f}, s2[4] = {0.f, 0.f, 0.f, 0.f};
#pragma unroll
    for (int mi = 0; mi < 4; ++mi) {
#pragma unroll
        for (int r = 0; r < 4; ++r) {
            int ix = wm * 64 + mi * 16 + q * 4 + r;
#pragma unroll
            for (int ni = 0; ni < 4; ++ni) {
                int nl = wn * 64 + ni * 16 + l16;
                float v = acc[mi][ni][r]
                        + b2f(g1s[(ix >> 1) * 128 + nl])
                        + b2f(g2s[(ix >> 2) * 128 + nl])
                        + b2f(g3s[(ix >> 3) * 128 + nl])
                        + pecs[(ix & 7) * 128 + nl];
                Y[(size_t)(m0 + ix) * 512 + (n0 + nl)] = f2b(v);
                s1[ni] += v;
                s2[ni] += v * v;
            }
        }
    }
#pragma unroll
    for (int ni = 0; ni < 4; ++ni) {
        float a = s1[ni], bq = s2[ni];
        a += __shfl_xor(a, 16); a += __shfl_xor(a, 32);
        bq += __shfl_xor(bq, 16); bq += __shfl_xor(bq, 32);
        if (q == 0) {
            int n = n0 + wn * 64 + ni * 16 + l16;
            atomicAdd(&stats[n], a);
            atomicAdd(&stats[512 + n], bq);
        }
    }
}

// ---------------- BN finalize ----------------
__global__ void finalize_bn(const float* __restrict__ stats, const float* __restrict__ g,
                            const float* __restrict__ be, float* __restrict__ bnp, int N) {
    int n = blockIdx.x * blockDim.x + threadIdx.x;
    if (n >= N) return;
    float inv = 1.0f / (float)MTOT;
    float mean = stats[n] * inv;
    float var = stats[N + n] * inv - mean * mean;
    float sc = g[n] * rsqrtf(var + 1e-5f);
    bnp[n] = sc;
    bnp[N + n] = be[n] - mean * sc;
}

// ---------------- in-place BN + ReLU on bf16 [M][N] ----------------
__global__ void bn_relu(u16* __restrict__ Y, const float* __restrict__ bnp,
                        int N, int nmask8, int total8) {
    const float* scale = bnp;
    const float* shift = bnp + N;
    for (int i = blockIdx.x * 256 + threadIdx.x; i < total8; i += gridDim.x * 256) {
        int nb = (i & nmask8) * 8;
        uint4 v = *(const uint4*)&Y[(size_t)i * 8];
        uint32_t w[4] = {v.x, v.y, v.z, v.w};
        uint32_t o[4];
#pragma unroll
        for (int p = 0; p < 4; ++p) {
            int n = nb + p * 2;
            float f0 = __uint_as_float(w[p] << 16);
            float f1 = __uint_as_float(w[p] & 0xffff0000u);
            f0 = fmaxf(f0 * scale[n] + shift[n], 0.f);
            f1 = fmaxf(f1 * scale[n + 1] + shift[n + 1], 0.f);
            o[p] = (uint32_t)f2b(f0) | ((uint32_t)f2b(f1) << 16);
        }
        *(uint4*)&Y[(size_t)i * 8] = make_uint4(o[0], o[1], o[2], o[3]);
    }
}

// ---------------- final: BN3+ReLU fused 256 -> 19 conv ----------------
__global__ __launch_bounds__(256) void gemm4_out(const u16* __restrict__ Y3,
                                                 const float* __restrict__ w4,
                                                 const float* __restrict__ b4,
                                                 const float* __restrict__ bnp3,
                                                 float* __restrict__ out) {
    __shared__ float w4s[19 * 256];
    int t = threadIdx.x;
    for (int i = t; i < 19 * 256; i += 256) w4s[i] = w4[i];
    __syncthreads();
    int mloc = t >> 4, l16 = t & 15;
    int m = blockIdx.x * 16 + mloc;
    float sc[16], sh[16];
#pragma unroll
    for (int j = 0; j < 16; ++j) {
        sc[j] = bnp3[l16 * 16 + j];
        sh[j] = bnp3[256 + l16 * 16 + j];
    }
    const uint4* yp = (const uint4*)((const char*)Y3 + (size_t)m * 512 + l16 * 32);
    uint4 v0 = yp[0], v1 = yp[1];
    uint32_t uu[8] = {v0.x, v0.y, v0.z, v0.w, v1.x, v1.y, v1.z, v1.w};
    float y[16];
#pragma unroll
    for (int p = 0; p < 8; ++p) {
        y[p * 2]     = __uint_as_float(uu[p] << 16);
        y[p * 2 + 1] = __uint_as_float(uu[p] & 0xffff0000u);
    }
#pragma unroll
    for (int j = 0; j < 16; ++j) y[j] = fmaxf(y[j] * sc[j] + sh[j], 0.f);
    float accv[19];
#pragma unroll
    for (int c = 0; c < 19; ++c) {
        const float* wr = &w4s[c * 256 + l16 * 16];
        float s = 0.f;
#pragma unroll
        for (int j = 0; j < 16; ++j) s += y[j] * wr[j];
        accv[c] = s;
    }
#pragma unroll
    for (int c = 0; c < 19; ++c) {
        float s = accv[c];
        s += __shfl_xor(s, 8, 16);
        s += __shfl_xor(s, 4, 16);
        s += __shfl_xor(s, 2, 16);
        s += __shfl_xor(s, 1, 16);
        accv[c] = s;
    }
    if (l16 == 0) {
        int b = m >> 14, l = m & 16383;
#pragma unroll
        for (int c = 0; c < 19; ++c)
            out[((size_t)b * 19 + c) * 16384 + l] = accv[c] + b4[c];
    }
}

extern "C" void kernel_launch(void* const* d_in, const int* in_sizes, int n_in,
                              void* d_out, int out_size, void* d_ws, size_t ws_size,
                              hipStream_t stream) {
    const float* x1 = (const float*)d_in[0];
    const float* x2 = (const float*)d_in[1];
    const float* x3 = (const float*)d_in[2];
    const float* x4 = (const float*)d_in[3];
    const float* w1 = (const float*)d_in[4];
    const float* b1 = (const float*)d_in[5];
    const float* g1 = (const float*)d_in[6];
    const float* be1 = (const float*)d_in[7];
    const float* w2 = (const float*)d_in[8];
    const float* b2 = (const float*)d_in[9];
    const float* g2 = (const float*)d_in[10];
    const float* be2 = (const float*)d_in[11];
    const float* w3 = (const float*)d_in[12];
    const float* b3 = (const float*)d_in[13];
    const float* g3 = (const float*)d_in[14];
    const float* be3 = (const float*)d_in[15];
    const float* w4 = (const float*)d_in[16];
    const float* b4 = (const float*)d_in[17];

    char* ws = (char*)d_ws;
    u16* A0  = (u16*)(ws + 0);            // [65536][256] — reused as Y3
    u16* Y3  = (u16*)(ws + 0);
    u16* A1  = (u16*)(ws + 33554432);     // [16384][256]
    u16* A2  = (u16*)(ws + 41943040);     // [4096][256]
    u16* A3  = (u16*)(ws + 44040192);     // [1024][256]
    u16* G1  = (u16*)(ws + 44564480);     // [16384][512]
    u16* G2  = (u16*)(ws + 61341696);     // [4096][512]
    u16* G3  = (u16*)(ws + 65536000);     // [1024][512]
    u16* Y2  = (u16*)(ws + 33554432);     // [65536][256] reuses A1..G3 region
    u16* Y1  = (u16*)(ws + 67108864);     // [65536][512]
    u16* wb1f = (u16*)(ws + 134217728);   // [4][512][256]
    u16* wb2 = (u16*)(ws + 135266304);    // [256][512]
    u16* wb3 = (u16*)(ws + 135528448);    // [256][256]
    float* pec = (float*)(ws + 135659520);// [64][512] f32
    float* stats = (float*)(ws + 135790592);
    float* bnp   = (float*)(ws + 135802880);

    zero_stats<<<12, 256, 0, stream>>>(stats);
    build_pec<<<64, 512, 0, stream>>>(w1, b1, pec);
    cvt_w1f<<<512, 256, 0, stream>>>(w1, wb1f);
    cvt_flat<<<256, 256, 0, stream>>>(w2, wb2, 256 * 512);
    cvt_flat<<<128, 256, 0, stream>>>(w3, wb3, 256 * 256);

    cvt_tr<<<256, 256, 0, stream>>>(x2, A1, 12);
    cvt_tr<<<64, 256, 0, stream>>>(x3, A2, 10);
    cvt_tr<<<16, 256, 0, stream>>>(x4, A3, 8);
    gemm_levels<<<dim3(4, 168), 256, 0, stream>>>(wb1f, A1, A2, A3, G1, G2, G3);

    cvt_tr<<<1024, 256, 0, stream>>>(x1, A0, 14);
    gemm_f1<<<dim3(4, 512), 256, 0, stream>>>(wb1f, A0, G1, G2, G3, pec, Y1, stats);
    finalize_bn<<<2, 256, 0, stream>>>(stats, g1, be1, bnp, 512);
    bn_relu<<<2048, 256, 0, stream>>>(Y1, bnp, 512, 63, 65536 * 64);

    gemm_bt<<<dim3(2, 512), 256, 0, stream>>>(wb2, Y1, b2, Y2, stats + 1024, 256, 512);
    finalize_bn<<<1, 256, 0, stream>>>(stats + 1024, g2, be2, bnp + 1024, 256);
    bn_relu<<<2048, 256, 0, stream>>>(Y2, bnp + 1024, 256, 31, 65536 * 32);

    gemm_bt<<<dim3(2, 512), 256, 0, stream>>>(wb3, Y2, b3, Y3, stats + 2048, 256, 256);
    finalize_bn<<<1, 256, 0, stream>>>(stats + 2048, g3, be3, bnp + 2048, 256);

    gemm4_out<<<4096, 256, 0, stream>>>(Y3, w4, b4, bnp + 2048, (float*)d_out);
}

// Round 5
// 289.060 us; speedup vs baseline: 1.1024x; 1.1024x over previous
//
#include <hip/hip_runtime.h>
#include <hip/hip_bf16.h>
#include <stdint.h>

typedef unsigned short u16;
typedef __bf16 bf16x8 __attribute__((ext_vector_type(8)));
typedef float f32x4 __attribute__((ext_vector_type(4)));

#define MTOT 65536

__device__ __forceinline__ u16 f2b(float f) {
    uint32_t u = __float_as_uint(f);
    u += 0x7fffu + ((u >> 16) & 1u);
    return (u16)(u >> 16);
}
__device__ __forceinline__ float b2f(u16 h) {
    return __uint_as_float(((uint32_t)h) << 16);
}

__device__ __forceinline__ void gload16(const void* g, void* l) {
    __builtin_amdgcn_global_load_lds((const __attribute__((address_space(1))) void*)g,
                                     (__attribute__((address_space(3))) void*)l, 16, 0, 0);
}

// stage one 128x64 bf16 operand tile (row-major, 128B rows) via global_load_lds.
__device__ __forceinline__ void stage_tile(const char* gbase, size_t ldb,
                                           u16* lbuf, int wave, int lane) {
    const char* src = gbase + (size_t)(wave * 32 + (lane >> 3)) * ldb + (lane & 7) * 16;
#pragma unroll
    for (int i = 0; i < 4; ++i)
        gload16(src + (size_t)i * 8 * ldb, lbuf + (wave * 32 + i * 8) * 64);
}

__device__ __forceinline__ void compute64(const u16* As, const u16* Ws, int wm, int wn,
                                          int l16, int q, f32x4 (&acc)[4][4]) {
#pragma unroll
    for (int kk = 0; kk < 64; kk += 32) {
        bf16x8 af[4], wf[4];
#pragma unroll
        for (int mi = 0; mi < 4; ++mi)
            af[mi] = *(const bf16x8*)&As[(wm * 64 + mi * 16 + l16) * 64 + kk + q * 8];
#pragma unroll
        for (int ni = 0; ni < 4; ++ni)
            wf[ni] = *(const bf16x8*)&Ws[(wn * 64 + ni * 16 + l16) * 64 + kk + q * 8];
#pragma unroll
        for (int mi = 0; mi < 4; ++mi)
#pragma unroll
            for (int ni = 0; ni < 4; ++ni)
                acc[mi][ni] = __builtin_amdgcn_mfma_f32_16x16x32_bf16(af[mi], wf[ni], acc[mi][ni], 0, 0, 0);
    }
}

// BN+ReLU on 8 bf16 channels held in a uint4 (channels are consecutive along k)
__device__ __forceinline__ uint4 bn8(uint4 v, const float* __restrict__ sc,
                                     const float* __restrict__ sh) {
    f32x4 s0 = *(const f32x4*)sc, s1 = *(const f32x4*)(sc + 4);
    f32x4 h0 = *(const f32x4*)sh, h1 = *(const f32x4*)(sh + 4);
    float sa[8] = {s0[0], s0[1], s0[2], s0[3], s1[0], s1[1], s1[2], s1[3]};
    float ha[8] = {h0[0], h0[1], h0[2], h0[3], h1[0], h1[1], h1[2], h1[3]};
    uint32_t w[4] = {v.x, v.y, v.z, v.w};
    uint32_t r[4];
#pragma unroll
    for (int p = 0; p < 4; ++p) {
        float f0 = __uint_as_float(w[p] << 16);
        float f1 = __uint_as_float(w[p] & 0xffff0000u);
        f0 = fmaxf(f0 * sa[2 * p] + ha[2 * p], 0.f);
        f1 = fmaxf(f1 * sa[2 * p + 1] + ha[2 * p + 1], 0.f);
        r[p] = (uint32_t)f2b(f0) | ((uint32_t)f2b(f1) << 16);
    }
    return make_uint4(r[0], r[1], r[2], r[3]);
}

// XCD-aware bijective swizzle (nwg % 8 == 0 required)
__device__ __forceinline__ int xcd_swz(int flat, int nwg) {
    int chunk = nwg >> 3;
    return (flat & 7) * chunk + (flat >> 3);
}

// ---------------- zero stats ----------------
__global__ void zero_stats(float* __restrict__ p) {
    int i = blockIdx.x * 256 + threadIdx.x;
    if (i < 3072) p[i] = 0.f;
}

// ---------------- PE table: PEC[(dy*8+dx)][n] ----------------
__global__ __launch_bounds__(512) void build_pec(const float* __restrict__ w1,
                                                 const float* __restrict__ b1,
                                                 float* __restrict__ pec) {
    __shared__ float pe[168];
    int dy = blockIdx.x >> 3, dx = blockIdx.x & 7;
    int t = threadIdx.x;
    if (t < 168) {
        int lv = t / 42, j = t - lv * 42;
        int msk = (1 << lv) - 1;
        float inv = 1.0f / (float)(1 << lv);
        float ry = (float)(2 * (dy & msk) + 1) * inv - 1.0f;
        float rx = (float)(2 * (dx & msk) + 1) * inv - 1.0f;
        float v;
        if (j == 0) v = ry;
        else if (j == 1) v = rx;
        else if (j < 12)  v = sinf(exp2f((float)(j - 2)  * (2.0f/3.0f)) * ry);
        else if (j < 22)  v = sinf(exp2f((float)(j - 12) * (2.0f/3.0f)) * rx);
        else if (j < 32)  v = cosf(exp2f((float)(j - 22) * (2.0f/3.0f)) * ry);
        else              v = cosf(exp2f((float)(j - 32) * (2.0f/3.0f)) * rx);
        pe[t] = v;
    }
    __syncthreads();
    int n = t;
    float acc = b1[n];
#pragma unroll 4
    for (int lv = 0; lv < 4; ++lv)
        for (int j = 0; j < 42; ++j)
            acc += pe[lv * 42 + j] * w1[n * 1192 + lv * 298 + j];
    pec[(size_t)blockIdx.x * 512 + n] = acc;
}

// ---------------- W1 feature-part extract ----------------
__global__ void cvt_w1f(const float* __restrict__ w1, u16* __restrict__ dst) {
    for (int i = blockIdx.x * 256 + threadIdx.x; i < 4 * 512 * 256; i += gridDim.x * 256) {
        int lv = i >> 17;
        int rem = i & 131071;
        int n = rem >> 8, c = rem & 255;
        dst[i] = f2b(w1[n * 1192 + lv * 298 + 42 + c]);
    }
}

// ---------------- flat f32 -> bf16 ----------------
__global__ void cvt_flat(const float* __restrict__ src, u16* __restrict__ dst, int total) {
    for (int i = blockIdx.x * 256 + threadIdx.x; i < total; i += gridDim.x * 256)
        dst[i] = f2b(src[i]);
}

// ---------------- transpose+convert x [B][256][plane] f32 -> A [B*plane][256] bf16
__global__ __launch_bounds__(256) void cvt_tr(const float* __restrict__ xs,
                                              u16* __restrict__ A, int shift) {
    __shared__ float sm[64][65];
    int t = threadIdx.x;
    int p0 = blockIdx.x * 64;
    int pix = t & 63, c0 = t >> 6;
    int plane = 1 << shift;
    int gp = p0 + pix;
    int b = gp >> shift;
    int l = gp & (plane - 1);
    const float* src = xs + ((size_t)b * 256) * plane + l;
    for (int cblk = 0; cblk < 4; ++cblk) {
#pragma unroll
        for (int it = 0; it < 16; ++it) {
            int c = it * 4 + c0;
            sm[pix][c] = src[(size_t)(cblk * 64 + c) * plane];
        }
        __syncthreads();
#pragma unroll
        for (int it = 0; it < 2; ++it) {
            int u = it * 256 + t;
            int ml = u >> 3, c8 = u & 7;
            const float* sr = &sm[ml][c8 * 8];
            uint4 v;
            v.x = (uint32_t)f2b(sr[0]) | ((uint32_t)f2b(sr[1]) << 16);
            v.y = (uint32_t)f2b(sr[2]) | ((uint32_t)f2b(sr[3]) << 16);
            v.z = (uint32_t)f2b(sr[4]) | ((uint32_t)f2b(sr[5]) << 16);
            v.w = (uint32_t)f2b(sr[6]) | ((uint32_t)f2b(sr[7]) << 16);
            *(uint4*)&A[(size_t)(p0 + ml) * 256 + cblk * 64 + c8 * 8] = v;
        }
        __syncthreads();
    }
}

// ---------------- fused BN+ReLU(A) GEMM: Y[m][n] = sum_k relu(A[m][k]*sc[k]+sh[k]) * W[n][k] + bias ----------------
// 128x128 tile, BK=64, dbuf; A reg-staged (BN applied en route), W via global_load_lds.
__global__ __launch_bounds__(256) void gemm_bn(const u16* __restrict__ W,
                                               const u16* __restrict__ Act,
                                               const float* __restrict__ scale,
                                               const float* __restrict__ shift,
                                               const float* __restrict__ bias,
                                               u16* __restrict__ Y,
                                               float* __restrict__ stats, int N, int K) {
    __shared__ u16 As[2][8192];
    __shared__ u16 Ws[2][8192];
    int tid = threadIdx.x;
    int wave = tid >> 6, lane = tid & 63;
    int wm = wave >> 1, wn = wave & 1;
    int nwg = gridDim.x * gridDim.y;
    int swz = xcd_swz(blockIdx.y * gridDim.x + blockIdx.x, nwg);
    int n0 = (swz % gridDim.x) * 128, m0 = (swz / gridDim.x) * 128;
    int q = lane >> 4, l16 = lane & 15;
    f32x4 acc[4][4];
#pragma unroll
    for (int i = 0; i < 4; ++i)
#pragma unroll
        for (int j = 0; j < 4; ++j) acc[i][j] = {0.f, 0.f, 0.f, 0.f};
    int lr = lane >> 3, ch = lane & 7;
    size_t ldb = (size_t)K * 2;
    const char* actb = (const char*)Act + (size_t)m0 * ldb + ch * 16;
    const char* wb = (const char*)W + (size_t)n0 * ldb;
    // prologue (kt = 0)
    uint4 rg[4];
#pragma unroll
    for (int i = 0; i < 4; ++i)
        rg[i] = *(const uint4*)(actb + (size_t)(wave * 32 + i * 8 + lr) * ldb);
    stage_tile(wb, ldb, Ws[0], wave, lane);
    {
        const float* sc = scale + ch * 8;
        const float* sh = shift + ch * 8;
#pragma unroll
        for (int i = 0; i < 4; ++i)
            *(uint4*)&As[0][(wave * 32 + i * 8 + lr) * 64 + ch * 8] = bn8(rg[i], sc, sh);
    }
    __syncthreads();
    int cur = 0;
    for (int kt = 64; kt < K; kt += 64) {
        // issue next A-tile loads early (latency hides under compute64)
#pragma unroll
        for (int i = 0; i < 4; ++i)
            rg[i] = *(const uint4*)(actb + (size_t)(wave * 32 + i * 8 + lr) * ldb + kt * 2);
        stage_tile(wb + kt * 2, ldb, Ws[cur ^ 1], wave, lane);
        compute64(As[cur], Ws[cur], wm, wn, l16, q, acc);
        const float* sc = scale + kt + ch * 8;
        const float* sh = shift + kt + ch * 8;
#pragma unroll
        for (int i = 0; i < 4; ++i)
            *(uint4*)&As[cur ^ 1][(wave * 32 + i * 8 + lr) * 64 + ch * 8] = bn8(rg[i], sc, sh);
        __syncthreads();
        cur ^= 1;
    }
    compute64(As[cur], Ws[cur], wm, wn, l16, q, acc);

    float bv[4];
#pragma unroll
    for (int ni = 0; ni < 4; ++ni)
        bv[ni] = bias[n0 + wn * 64 + ni * 16 + l16];
    float s1[4] = {0.f, 0.f, 0.f, 0.f}, s2[4] = {0.f, 0.f, 0.f, 0.f};
#pragma unroll
    for (int mi = 0; mi < 4; ++mi) {
#pragma unroll
        for (int r = 0; r < 4; ++r) {
            int m = m0 + wm * 64 + mi * 16 + q * 4 + r;
#pragma unroll
            for (int ni = 0; ni < 4; ++ni) {
                float v = acc[mi][ni][r] + bv[ni];
                Y[(size_t)m * N + (n0 + wn * 64 + ni * 16 + l16)] = f2b(v);
                s1[ni] += v;
                s2[ni] += v * v;
            }
        }
    }
    if (stats) {
#pragma unroll
        for (int ni = 0; ni < 4; ++ni) {
            float a = s1[ni], bq = s2[ni];
            a += __shfl_xor(a, 16); a += __shfl_xor(a, 32);
            bq += __shfl_xor(bq, 16); bq += __shfl_xor(bq, 32);
            if (q == 0) {
                int n = n0 + wn * 64 + ni * 16 + l16;
                atomicAdd(&stats[n], a);
                atomicAdd(&stats[N + n], bq);
            }
        }
    }
}

// ---------------- merged low-res level GEMMs: G_lv = A_lv * W_lv^T ----------------
__global__ __launch_bounds__(256) void gemm_levels(const u16* __restrict__ wb1f,
                                                   const u16* __restrict__ A1,
                                                   const u16* __restrict__ A2,
                                                   const u16* __restrict__ A3,
                                                   u16* __restrict__ G1,
                                                   u16* __restrict__ G2,
                                                   u16* __restrict__ G3) {
    __shared__ u16 As[2][8192];
    __shared__ u16 Ws[2][8192];
    int tid = threadIdx.x;
    int wave = tid >> 6, lane = tid & 63;
    int wm = wave >> 1, wn = wave & 1;
    int swz = xcd_swz(blockIdx.y * 4 + blockIdx.x, 672);
    int bx = swz & 3, by = swz >> 2;
    const u16* A; u16* G; const u16* W;
    int mt;
    if (by < 128)      { A = A1; G = G1; W = wb1f + 1 * 131072; mt = by; }
    else if (by < 160) { A = A2; G = G2; W = wb1f + 2 * 131072; mt = by - 128; }
    else               { A = A3; G = G3; W = wb1f + 3 * 131072; mt = by - 160; }
    int n0 = bx * 128, m0 = mt * 128;
    int q = lane >> 4, l16 = lane & 15;
    f32x4 acc[4][4];
#pragma unroll
    for (int i = 0; i < 4; ++i)
#pragma unroll
        for (int j = 0; j < 4; ++j) acc[i][j] = {0.f, 0.f, 0.f, 0.f};
    const char* actb = (const char*)A + (size_t)m0 * 512;
    const char* wb = (const char*)W + (size_t)n0 * 512;
    stage_tile(actb, 512, As[0], wave, lane);
    stage_tile(wb, 512, Ws[0], wave, lane);
    __syncthreads();
    int cur = 0;
#pragma unroll
    for (int kt = 0; kt < 4; ++kt) {
        if (kt < 3) {
            stage_tile(actb + (kt + 1) * 128, 512, As[cur ^ 1], wave, lane);
            stage_tile(wb + (kt + 1) * 128, 512, Ws[cur ^ 1], wave, lane);
        }
        compute64(As[cur], Ws[cur], wm, wn, l16, q, acc);
        __syncthreads();
        cur ^= 1;
    }
#pragma unroll
    for (int mi = 0; mi < 4; ++mi)
#pragma unroll
        for (int r = 0; r < 4; ++r) {
            int m = m0 + wm * 64 + mi * 16 + q * 4 + r;
#pragma unroll
            for (int ni = 0; ni < 4; ++ni)
                G[(size_t)m * 512 + (n0 + wn * 64 + ni * 16 + l16)] = f2b(acc[mi][ni][r]);
        }
}

// ---------------- fused layer-1 GEMM + gathers + PEC + stats ----------------
__global__ __launch_bounds__(256) void gemm_f1(const u16* __restrict__ W,
                                               const u16* __restrict__ A0,
                                               const u16* __restrict__ G1,
                                               const u16* __restrict__ G2,
                                               const u16* __restrict__ G3,
                                               const float* __restrict__ pec,
                                               u16* __restrict__ Y,
                                               float* __restrict__ stats) {
    __shared__ u16 As[2][8192];
    __shared__ u16 Ws[2][8192];
    int tid = threadIdx.x;
    int wave = tid >> 6, lane = tid & 63;
    int wm = wave >> 1, wn = wave & 1;
    int swz = xcd_swz(blockIdx.y * 4 + blockIdx.x, 2048);
    int n0 = (swz & 3) * 128, m0 = (swz >> 2) * 128;
    int q = lane >> 4, l16 = lane & 15;
    f32x4 acc[4][4];
#pragma unroll
    for (int i = 0; i < 4; ++i)
#pragma unroll
        for (int j = 0; j < 4; ++j) acc[i][j] = {0.f, 0.f, 0.f, 0.f};
    const char* actb = (const char*)A0 + (size_t)m0 * 512;
    const char* wb = (const char*)W + (size_t)n0 * 512;
    stage_tile(actb, 512, As[0], wave, lane);
    stage_tile(wb, 512, Ws[0], wave, lane);
    __syncthreads();
    int cur = 0;
#pragma unroll
    for (int kt = 0; kt < 4; ++kt) {
        if (kt < 3) {
            stage_tile(actb + (kt + 1) * 128, 512, As[cur ^ 1], wave, lane);
            stage_tile(wb + (kt + 1) * 128, 512, Ws[cur ^ 1], wave, lane);
        }
        compute64(As[cur], Ws[cur], wm, wn, l16, q, acc);
        __syncthreads();
        cur ^= 1;
    }
    // ---- epilogue: stage gather rows in LDS (reuses As/Ws; barrier above protects) ----
    u16* g1s = &As[0][0];                     // [64][128] 16KB (spans As)
    u16* g2s = &Ws[0][0];                     // [32][128] 8KB
    u16* g3s = &Ws[0][0] + 4096;              // [16][128] 4KB
    float* pecs = (float*)(&Ws[0][0] + 6144); // [8][128] 4KB
    int b = m0 >> 14;
    int iy = (m0 >> 7) & 127;
    {
        const u16* g1p = G1 + ((size_t)(b * 4096 + (iy >> 1) * 64)) * 512 + n0;
#pragma unroll
        for (int it = 0; it < 4; ++it) {
            int u = it * 256 + tid;
            int row = u >> 4, c8 = u & 15;
            *(uint4*)&g1s[row * 128 + c8 * 8] = *(const uint4*)&g1p[(size_t)row * 512 + c8 * 8];
        }
        const u16* g2p = G2 + ((size_t)(b * 1024 + (iy >> 2) * 32)) * 512 + n0;
#pragma unroll
        for (int it = 0; it < 2; ++it) {
            int u = it * 256 + tid;
            int row = u >> 4, c8 = u & 15;
            *(uint4*)&g2s[row * 128 + c8 * 8] = *(const uint4*)&g2p[(size_t)row * 512 + c8 * 8];
        }
        const u16* g3p = G3 + ((size_t)(b * 256 + (iy >> 3) * 16)) * 512 + n0;
        {
            int row = tid >> 4, c8 = tid & 15;
            *(uint4*)&g3s[row * 128 + c8 * 8] = *(const uint4*)&g3p[(size_t)row * 512 + c8 * 8];
        }
        const float* pp = pec + (size_t)((iy & 7) * 8) * 512 + n0;
        {
            int row = tid >> 5, c4 = tid & 31;
            *(uint4*)&pecs[row * 128 + c4 * 4] = *(const uint4*)&pp[(size_t)row * 512 + c4 * 4];
        }
    }
    __syncthreads();
    float s1[4] = {0.f, 0.f, 0.f, 0.f}, s2[4] = {0.f, 0.f, 0.f, 0.f};
#pragma unroll
    for (int mi = 0; mi < 4; ++mi) {
#pragma unroll
        for (int r = 0; r < 4; ++r) {
            int ix = wm * 64 + mi * 16 + q * 4 + r;
#pragma unroll
            for (int ni = 0; ni < 4; ++ni) {
                int nl = wn * 64 + ni * 16 + l16;
                float v = acc[mi][ni][r]
                        + b2f(g1s[(ix >> 1) * 128 + nl])
                        + b2f(g2s[(ix >> 2) * 128 + nl])
                        + b2f(g3s[(ix >> 3) * 128 + nl])
                        + pecs[(ix & 7) * 128 + nl];
                Y[(size_t)(m0 + ix) * 512 + (n0 + nl)] = f2b(v);
                s1[ni] += v;
                s2[ni] += v * v;
            }
        }
    }
#pragma unroll
    for (int ni = 0; ni < 4; ++ni) {
        float a = s1[ni], bq = s2[ni];
        a += __shfl_xor(a, 16); a += __shfl_xor(a, 32);
        bq += __shfl_xor(bq, 16); bq += __shfl_xor(bq, 32);
        if (q == 0) {
            int n = n0 + wn * 64 + ni * 16 + l16;
            atomicAdd(&stats[n], a);
            atomicAdd(&stats[512 + n], bq);
        }
    }
}

// ---------------- BN finalize ----------------
__global__ void finalize_bn(const float* __restrict__ stats, const float* __restrict__ g,
                            const float* __restrict__ be, float* __restrict__ bnp, int N) {
    int n = blockIdx.x * blockDim.x + threadIdx.x;
    if (n >= N) return;
    float inv = 1.0f / (float)MTOT;
    float mean = stats[n] * inv;
    float var = stats[N + n] * inv - mean * mean;
    float sc = g[n] * rsqrtf(var + 1e-5f);
    bnp[n] = sc;
    bnp[N + n] = be[n] - mean * sc;
}

// ---------------- final: BN3+ReLU fused 256 -> 19 conv ----------------
__global__ __launch_bounds__(256) void gemm4_out(const u16* __restrict__ Y3,
                                                 const float* __restrict__ w4,
                                                 const float* __restrict__ b4,
                                                 const float* __restrict__ bnp3,
                                                 float* __restrict__ out) {
    __shared__ float w4s[19 * 256];
    int t = threadIdx.x;
    for (int i = t; i < 19 * 256; i += 256) w4s[i] = w4[i];
    __syncthreads();
    int mloc = t >> 4, l16 = t & 15;
    int m = blockIdx.x * 16 + mloc;
    float sc[16], sh[16];
#pragma unroll
    for (int j = 0; j < 16; ++j) {
        sc[j] = bnp3[l16 * 16 + j];
        sh[j] = bnp3[256 + l16 * 16 + j];
    }
    const uint4* yp = (const uint4*)((const char*)Y3 + (size_t)m * 512 + l16 * 32);
    uint4 v0 = yp[0], v1 = yp[1];
    uint32_t uu[8] = {v0.x, v0.y, v0.z, v0.w, v1.x, v1.y, v1.z, v1.w};
    float y[16];
#pragma unroll
    for (int p = 0; p < 8; ++p) {
        y[p * 2]     = __uint_as_float(uu[p] << 16);
        y[p * 2 + 1] = __uint_as_float(uu[p] & 0xffff0000u);
    }
#pragma unroll
    for (int j = 0; j < 16; ++j) y[j] = fmaxf(y[j] * sc[j] + sh[j], 0.f);
    float accv[19];
#pragma unroll
    for (int c = 0; c < 19; ++c) {
        const float* wr = &w4s[c * 256 + l16 * 16];
        float s = 0.f;
#pragma unroll
        for (int j = 0; j < 16; ++j) s += y[j] * wr[j];
        accv[c] = s;
    }
#pragma unroll
    for (int c = 0; c < 19; ++c) {
        float s = accv[c];
        s += __shfl_xor(s, 8, 16);
        s += __shfl_xor(s, 4, 16);
        s += __shfl_xor(s, 2, 16);
        s += __shfl_xor(s, 1, 16);
        accv[c] = s;
    }
    if (l16 == 0) {
        int b = m >> 14, l = m & 16383;
#pragma unroll
        for (int c = 0; c < 19; ++c)
            out[((size_t)b * 19 + c) * 16384 + l] = accv[c] + b4[c];
    }
}

extern "C" void kernel_launch(void* const* d_in, const int* in_sizes, int n_in,
                              void* d_out, int out_size, void* d_ws, size_t ws_size,
                              hipStream_t stream) {
    const float* x1 = (const float*)d_in[0];
    const float* x2 = (const float*)d_in[1];
    const float* x3 = (const float*)d_in[2];
    const float* x4 = (const float*)d_in[3];
    const float* w1 = (const float*)d_in[4];
    const float* b1 = (const float*)d_in[5];
    const float* g1 = (const float*)d_in[6];
    const float* be1 = (const float*)d_in[7];
    const float* w2 = (const float*)d_in[8];
    const float* b2 = (const float*)d_in[9];
    const float* g2 = (const float*)d_in[10];
    const float* be2 = (const float*)d_in[11];
    const float* w3 = (const float*)d_in[12];
    const float* b3 = (const float*)d_in[13];
    const float* g3 = (const float*)d_in[14];
    const float* be3 = (const float*)d_in[15];
    const float* w4 = (const float*)d_in[16];
    const float* b4 = (const float*)d_in[17];

    char* ws = (char*)d_ws;
    u16* A0  = (u16*)(ws + 0);            // [65536][256] — reused as Y3
    u16* Y3  = (u16*)(ws + 0);
    u16* A1  = (u16*)(ws + 33554432);     // [16384][256]
    u16* A2  = (u16*)(ws + 41943040);     // [4096][256]
    u16* A3  = (u16*)(ws + 44040192);     // [1024][256]
    u16* G1  = (u16*)(ws + 44564480);     // [16384][512]
    u16* G2  = (u16*)(ws + 61341696);     // [4096][512]
    u16* G3  = (u16*)(ws + 65536000);     // [1024][512]
    u16* Y2  = (u16*)(ws + 33554432);     // [65536][256] reuses A1..G3 region
    u16* Y1  = (u16*)(ws + 67108864);     // [65536][512]
    u16* wb1f = (u16*)(ws + 134217728);   // [4][512][256]
    u16* wb2 = (u16*)(ws + 135266304);    // [256][512]
    u16* wb3 = (u16*)(ws + 135528448);    // [256][256]
    float* pec = (float*)(ws + 135659520);// [64][512] f32
    float* stats = (float*)(ws + 135790592);
    float* bnp   = (float*)(ws + 135802880);

    zero_stats<<<12, 256, 0, stream>>>(stats);
    build_pec<<<64, 512, 0, stream>>>(w1, b1, pec);
    cvt_w1f<<<512, 256, 0, stream>>>(w1, wb1f);
    cvt_flat<<<256, 256, 0, stream>>>(w2, wb2, 256 * 512);
    cvt_flat<<<128, 256, 0, stream>>>(w3, wb3, 256 * 256);

    cvt_tr<<<256, 256, 0, stream>>>(x2, A1, 12);
    cvt_tr<<<64, 256, 0, stream>>>(x3, A2, 10);
    cvt_tr<<<16, 256, 0, stream>>>(x4, A3, 8);
    gemm_levels<<<dim3(4, 168), 256, 0, stream>>>(wb1f, A1, A2, A3, G1, G2, G3);

    cvt_tr<<<1024, 256, 0, stream>>>(x1, A0, 14);
    gemm_f1<<<dim3(4, 512), 256, 0, stream>>>(wb1f, A0, G1, G2, G3, pec, Y1, stats);
    finalize_bn<<<2, 256, 0, stream>>>(stats, g1, be1, bnp, 512);

    // layer 2: BN1+ReLU fused into A-staging
    gemm_bn<<<dim3(2, 512), 256, 0, stream>>>(wb2, Y1, bnp, bnp + 512, b2, Y2,
                                              stats + 1024, 256, 512);
    finalize_bn<<<1, 256, 0, stream>>>(stats + 1024, g2, be2, bnp + 1024, 256);

    // layer 3: BN2+ReLU fused into A-staging
    gemm_bn<<<dim3(2, 512), 256, 0, stream>>>(wb3, Y2, bnp + 1024, bnp + 1024 + 256, b3, Y3,
                                              stats + 2048, 256, 256);
    finalize_bn<<<1, 256, 0, stream>>>(stats + 2048, g3, be3, bnp + 2048, 256);

    gemm4_out<<<4096, 256, 0, stream>>>(Y3, w4, b4, bnp + 2048, (float*)d_out);
}

// Round 6
// 283.107 us; speedup vs baseline: 1.1256x; 1.0210x over previous
//
#include <hip/hip_runtime.h>
#include <hip/hip_bf16.h>
#include <stdint.h>

typedef unsigned short u16;
typedef __bf16 bf16x8 __attribute__((ext_vector_type(8)));
typedef float f32x4 __attribute__((ext_vector_type(4)));

#define MTOT 65536

__device__ __forceinline__ u16 f2b(float f) {
    uint32_t u = __float_as_uint(f);
    u += 0x7fffu + ((u >> 16) & 1u);
    return (u16)(u >> 16);
}
__device__ __forceinline__ float b2f(u16 h) {
    return __uint_as_float(((uint32_t)h) << 16);
}

__device__ __forceinline__ void gload16(const void* g, void* l) {
    __builtin_amdgcn_global_load_lds((const __attribute__((address_space(1))) void*)g,
                                     (__attribute__((address_space(3))) void*)l, 16, 0, 0);
}

// stage one 128x64 bf16 operand tile (row-major, 128B rows) via global_load_lds.
__device__ __forceinline__ void stage_tile(const char* gbase, size_t ldb,
                                           u16* lbuf, int wave, int lane) {
    const char* src = gbase + (size_t)(wave * 32 + (lane >> 3)) * ldb + (lane & 7) * 16;
#pragma unroll
    for (int i = 0; i < 4; ++i)
        gload16(src + (size_t)i * 8 * ldb, lbuf + (wave * 32 + i * 8) * 64);
}

__device__ __forceinline__ void compute64(const u16* As, const u16* Ws, int wm, int wn,
                                          int l16, int q, f32x4 (&acc)[4][4]) {
#pragma unroll
    for (int kk = 0; kk < 64; kk += 32) {
        bf16x8 af[4], wf[4];
#pragma unroll
        for (int mi = 0; mi < 4; ++mi)
            af[mi] = *(const bf16x8*)&As[(wm * 64 + mi * 16 + l16) * 64 + kk + q * 8];
#pragma unroll
        for (int ni = 0; ni < 4; ++ni)
            wf[ni] = *(const bf16x8*)&Ws[(wn * 64 + ni * 16 + l16) * 64 + kk + q * 8];
#pragma unroll
        for (int mi = 0; mi < 4; ++mi)
#pragma unroll
            for (int ni = 0; ni < 4; ++ni)
                acc[mi][ni] = __builtin_amdgcn_mfma_f32_16x16x32_bf16(af[mi], wf[ni], acc[mi][ni], 0, 0, 0);
    }
}

// BN+ReLU on 8 bf16 channels held in a uint4 (channels are consecutive along k)
__device__ __forceinline__ uint4 bn8(uint4 v, const float* __restrict__ sc,
                                     const float* __restrict__ sh) {
    f32x4 s0 = *(const f32x4*)sc, s1 = *(const f32x4*)(sc + 4);
    f32x4 h0 = *(const f32x4*)sh, h1 = *(const f32x4*)(sh + 4);
    float sa[8] = {s0[0], s0[1], s0[2], s0[3], s1[0], s1[1], s1[2], s1[3]};
    float ha[8] = {h0[0], h0[1], h0[2], h0[3], h1[0], h1[1], h1[2], h1[3]};
    uint32_t w[4] = {v.x, v.y, v.z, v.w};
    uint32_t r[4];
#pragma unroll
    for (int p = 0; p < 4; ++p) {
        float f0 = __uint_as_float(w[p] << 16);
        float f1 = __uint_as_float(w[p] & 0xffff0000u);
        f0 = fmaxf(f0 * sa[2 * p] + ha[2 * p], 0.f);
        f1 = fmaxf(f1 * sa[2 * p + 1] + ha[2 * p + 1], 0.f);
        r[p] = (uint32_t)f2b(f0) | ((uint32_t)f2b(f1) << 16);
    }
    return make_uint4(r[0], r[1], r[2], r[3]);
}

// block remap: n-siblings of one m-tile land on the SAME XCD, adjacent in time.
template <int GX>
__device__ __forceinline__ void remap(int& bx, int& by) {
    int f = blockIdx.y * GX + blockIdx.x;
    int r = f & 7, s = f >> 3;
    bx = s % GX;
    by = r + (s / GX) * 8;
}

// XCD-aware bijective swizzle (nwg % 8 == 0 required)
__device__ __forceinline__ int xcd_swz(int flat, int nwg) {
    int chunk = nwg >> 3;
    return (flat & 7) * chunk + (flat >> 3);
}

// ---------------- zero stats ----------------
__global__ void zero_stats(float* __restrict__ p) {
    int i = blockIdx.x * 256 + threadIdx.x;
    if (i < 3072) p[i] = 0.f;
}

// ---------------- PE table: PEC[(dy*8+dx)][n] ----------------
__global__ __launch_bounds__(512) void build_pec(const float* __restrict__ w1,
                                                 const float* __restrict__ b1,
                                                 float* __restrict__ pec) {
    __shared__ float pe[168];
    int dy = blockIdx.x >> 3, dx = blockIdx.x & 7;
    int t = threadIdx.x;
    if (t < 168) {
        int lv = t / 42, j = t - lv * 42;
        int msk = (1 << lv) - 1;
        float inv = 1.0f / (float)(1 << lv);
        float ry = (float)(2 * (dy & msk) + 1) * inv - 1.0f;
        float rx = (float)(2 * (dx & msk) + 1) * inv - 1.0f;
        float v;
        if (j == 0) v = ry;
        else if (j == 1) v = rx;
        else if (j < 12)  v = sinf(exp2f((float)(j - 2)  * (2.0f/3.0f)) * ry);
        else if (j < 22)  v = sinf(exp2f((float)(j - 12) * (2.0f/3.0f)) * rx);
        else if (j < 32)  v = cosf(exp2f((float)(j - 22) * (2.0f/3.0f)) * ry);
        else              v = cosf(exp2f((float)(j - 32) * (2.0f/3.0f)) * rx);
        pe[t] = v;
    }
    __syncthreads();
    int n = t;
    float acc = b1[n];
#pragma unroll 4
    for (int lv = 0; lv < 4; ++lv)
        for (int j = 0; j < 42; ++j)
            acc += pe[lv * 42 + j] * w1[n * 1192 + lv * 298 + j];
    pec[(size_t)blockIdx.x * 512 + n] = acc;
}

// ---------------- W1 feature-part extract ----------------
__global__ void cvt_w1f(const float* __restrict__ w1, u16* __restrict__ dst) {
    for (int i = blockIdx.x * 256 + threadIdx.x; i < 4 * 512 * 256; i += gridDim.x * 256) {
        int lv = i >> 17;
        int rem = i & 131071;
        int n = rem >> 8, c = rem & 255;
        dst[i] = f2b(w1[n * 1192 + lv * 298 + 42 + c]);
    }
}

// ---------------- flat f32 -> bf16 ----------------
__global__ void cvt_flat(const float* __restrict__ src, u16* __restrict__ dst, int total) {
    for (int i = blockIdx.x * 256 + threadIdx.x; i < total; i += gridDim.x * 256)
        dst[i] = f2b(src[i]);
}

// ---------------- transpose+convert x [B][256][plane] f32 -> A [B*plane][256] bf16
__global__ __launch_bounds__(256) void cvt_tr(const float* __restrict__ xs,
                                              u16* __restrict__ A, int shift) {
    __shared__ float sm[64][65];
    int t = threadIdx.x;
    int p0 = blockIdx.x * 64;
    int pix = t & 63, c0 = t >> 6;
    int plane = 1 << shift;
    int gp = p0 + pix;
    int b = gp >> shift;
    int l = gp & (plane - 1);
    const float* src = xs + ((size_t)b * 256) * plane + l;
    for (int cblk = 0; cblk < 4; ++cblk) {
#pragma unroll
        for (int it = 0; it < 16; ++it) {
            int c = it * 4 + c0;
            sm[pix][c] = src[(size_t)(cblk * 64 + c) * plane];
        }
        __syncthreads();
#pragma unroll
        for (int it = 0; it < 2; ++it) {
            int u = it * 256 + t;
            int ml = u >> 3, c8 = u & 7;
            const float* sr = &sm[ml][c8 * 8];
            uint4 v;
            v.x = (uint32_t)f2b(sr[0]) | ((uint32_t)f2b(sr[1]) << 16);
            v.y = (uint32_t)f2b(sr[2]) | ((uint32_t)f2b(sr[3]) << 16);
            v.z = (uint32_t)f2b(sr[4]) | ((uint32_t)f2b(sr[5]) << 16);
            v.w = (uint32_t)f2b(sr[6]) | ((uint32_t)f2b(sr[7]) << 16);
            *(uint4*)&A[(size_t)(p0 + ml) * 256 + cblk * 64 + c8 * 8] = v;
        }
        __syncthreads();
    }
}

// ---------------- fused BN+ReLU(A) GEMM ----------------
__global__ __launch_bounds__(256) void gemm_bn(const u16* __restrict__ W,
                                               const u16* __restrict__ Act,
                                               const float* __restrict__ scale,
                                               const float* __restrict__ shift,
                                               const float* __restrict__ bias,
                                               u16* __restrict__ Y,
                                               float* __restrict__ stats, int N, int K) {
    __shared__ u16 As[2][8192];
    __shared__ u16 Ws[2][8192];
    int tid = threadIdx.x;
    int wave = tid >> 6, lane = tid & 63;
    int wm = wave >> 1, wn = wave & 1;
    int bx, by;
    remap<2>(bx, by);
    int n0 = bx * 128, m0 = by * 128;
    int q = lane >> 4, l16 = lane & 15;
    f32x4 acc[4][4];
#pragma unroll
    for (int i = 0; i < 4; ++i)
#pragma unroll
        for (int j = 0; j < 4; ++j) acc[i][j] = {0.f, 0.f, 0.f, 0.f};
    int lr = lane >> 3, ch = lane & 7;
    size_t ldb = (size_t)K * 2;
    const char* actb = (const char*)Act + (size_t)m0 * ldb + ch * 16;
    const char* wb = (const char*)W + (size_t)n0 * ldb;
    uint4 rg[4];
#pragma unroll
    for (int i = 0; i < 4; ++i)
        rg[i] = *(const uint4*)(actb + (size_t)(wave * 32 + i * 8 + lr) * ldb);
    stage_tile(wb, ldb, Ws[0], wave, lane);
    {
        const float* sc = scale + ch * 8;
        const float* sh = shift + ch * 8;
#pragma unroll
        for (int i = 0; i < 4; ++i)
            *(uint4*)&As[0][(wave * 32 + i * 8 + lr) * 64 + ch * 8] = bn8(rg[i], sc, sh);
    }
    __syncthreads();
    int cur = 0;
    for (int kt = 64; kt < K; kt += 64) {
#pragma unroll
        for (int i = 0; i < 4; ++i)
            rg[i] = *(const uint4*)(actb + (size_t)(wave * 32 + i * 8 + lr) * ldb + kt * 2);
        stage_tile(wb + kt * 2, ldb, Ws[cur ^ 1], wave, lane);
        compute64(As[cur], Ws[cur], wm, wn, l16, q, acc);
        const float* sc = scale + kt + ch * 8;
        const float* sh = shift + kt + ch * 8;
#pragma unroll
        for (int i = 0; i < 4; ++i)
            *(uint4*)&As[cur ^ 1][(wave * 32 + i * 8 + lr) * 64 + ch * 8] = bn8(rg[i], sc, sh);
        __syncthreads();
        cur ^= 1;
    }
    compute64(As[cur], Ws[cur], wm, wn, l16, q, acc);

    float bv[4];
#pragma unroll
    for (int ni = 0; ni < 4; ++ni)
        bv[ni] = bias[n0 + wn * 64 + ni * 16 + l16];
    float s1[4] = {0.f, 0.f, 0.f, 0.f}, s2[4] = {0.f, 0.f, 0.f, 0.f};
#pragma unroll
    for (int mi = 0; mi < 4; ++mi) {
#pragma unroll
        for (int r = 0; r < 4; ++r) {
            int m = m0 + wm * 64 + mi * 16 + q * 4 + r;
#pragma unroll
            for (int ni = 0; ni < 4; ++ni) {
                float v = acc[mi][ni][r] + bv[ni];
                Y[(size_t)m * N + (n0 + wn * 64 + ni * 16 + l16)] = f2b(v);
                s1[ni] += v;
                s2[ni] += v * v;
            }
        }
    }
    if (stats) {
#pragma unroll
        for (int ni = 0; ni < 4; ++ni) {
            float a = s1[ni], bq = s2[ni];
            a += __shfl_xor(a, 16); a += __shfl_xor(a, 32);
            bq += __shfl_xor(bq, 16); bq += __shfl_xor(bq, 32);
            if (q == 0) {
                int n = n0 + wn * 64 + ni * 16 + l16;
                atomicAdd(&stats[n], a);
                atomicAdd(&stats[N + n], bq);
            }
        }
    }
}

// ---------------- merged low-res level GEMMs ----------------
__global__ __launch_bounds__(256) void gemm_levels(const u16* __restrict__ wb1f,
                                                   const u16* __restrict__ A1,
                                                   const u16* __restrict__ A2,
                                                   const u16* __restrict__ A3,
                                                   u16* __restrict__ G1,
                                                   u16* __restrict__ G2,
                                                   u16* __restrict__ G3) {
    __shared__ u16 As[2][8192];
    __shared__ u16 Ws[2][8192];
    int tid = threadIdx.x;
    int wave = tid >> 6, lane = tid & 63;
    int wm = wave >> 1, wn = wave & 1;
    int swz = xcd_swz(blockIdx.y * 4 + blockIdx.x, 672);
    int bx = swz & 3, by = swz >> 2;
    const u16* A; u16* G; const u16* W;
    int mt;
    if (by < 128)      { A = A1; G = G1; W = wb1f + 1 * 131072; mt = by; }
    else if (by < 160) { A = A2; G = G2; W = wb1f + 2 * 131072; mt = by - 128; }
    else               { A = A3; G = G3; W = wb1f + 3 * 131072; mt = by - 160; }
    int n0 = bx * 128, m0 = mt * 128;
    int q = lane >> 4, l16 = lane & 15;
    f32x4 acc[4][4];
#pragma unroll
    for (int i = 0; i < 4; ++i)
#pragma unroll
        for (int j = 0; j < 4; ++j) acc[i][j] = {0.f, 0.f, 0.f, 0.f};
    const char* actb = (const char*)A + (size_t)m0 * 512;
    const char* wb = (const char*)W + (size_t)n0 * 512;
    stage_tile(actb, 512, As[0], wave, lane);
    stage_tile(wb, 512, Ws[0], wave, lane);
    __syncthreads();
    int cur = 0;
#pragma unroll
    for (int kt = 0; kt < 4; ++kt) {
        if (kt < 3) {
            stage_tile(actb + (kt + 1) * 128, 512, As[cur ^ 1], wave, lane);
            stage_tile(wb + (kt + 1) * 128, 512, Ws[cur ^ 1], wave, lane);
        }
        compute64(As[cur], Ws[cur], wm, wn, l16, q, acc);
        __syncthreads();
        cur ^= 1;
    }
#pragma unroll
    for (int mi = 0; mi < 4; ++mi)
#pragma unroll
        for (int r = 0; r < 4; ++r) {
            int m = m0 + wm * 64 + mi * 16 + q * 4 + r;
#pragma unroll
            for (int ni = 0; ni < 4; ++ni)
                G[(size_t)m * 512 + (n0 + wn * 64 + ni * 16 + l16)] = f2b(acc[mi][ni][r]);
        }
}

// ---------------- fused layer-1: x1 transpose-in-kernel GEMM + gathers + PEC + stats ----------------
// grid (4, 512). m-tile = one (b, iy) image row, ix 0..127. K = 256 channels of x1.
__global__ __launch_bounds__(256) void gemm_f1x(const u16* __restrict__ W,
                                                const float* __restrict__ x1,
                                                const u16* __restrict__ G1,
                                                const u16* __restrict__ G2,
                                                const u16* __restrict__ G3,
                                                const float* __restrict__ pec,
                                                u16* __restrict__ Y,
                                                float* __restrict__ stats) {
    __shared__ u16 As[2][8192];   // [128 px][64 ch] bf16
    __shared__ u16 Ws[2][8192];
    int tid = threadIdx.x;
    int wave = tid >> 6, lane = tid & 63;
    int wm = wave >> 1, wn = wave & 1;
    int bx, by;
    remap<4>(bx, by);
    int n0 = bx * 128, m0 = by * 128;
    int q = lane >> 4, l16 = lane & 15;
    f32x4 acc[4][4];
#pragma unroll
    for (int i = 0; i < 4; ++i)
#pragma unroll
        for (int j = 0; j < 4; ++j) acc[i][j] = {0.f, 0.f, 0.f, 0.f};
    int b = m0 >> 14;
    int iy = (m0 >> 7) & 127;
    // A-staging: thread t loads px = (t&31)*4..+3 of channels (t>>5)*8..+7
    int pxq = tid & 31, cb = tid >> 5;
    const float* aptr = x1 + ((size_t)b * 256 + cb * 8) * 16384 + (size_t)iy * 128 + pxq * 4;
    const char* wb = (const char*)W + (size_t)n0 * 512;

    uint4 rg[8];
#pragma unroll
    for (int j = 0; j < 8; ++j)
        rg[j] = *(const uint4*)(aptr + (size_t)j * 16384);
    stage_tile(wb, 512, Ws[0], wave, lane);
#pragma unroll
    for (int pi = 0; pi < 4; ++pi) {
        const float* rf = (const float*)rg;
        uint4 o;
        o.x = (uint32_t)f2b(rf[0 * 4 + pi]) | ((uint32_t)f2b(rf[1 * 4 + pi]) << 16);
        o.y = (uint32_t)f2b(rf[2 * 4 + pi]) | ((uint32_t)f2b(rf[3 * 4 + pi]) << 16);
        o.z = (uint32_t)f2b(rf[4 * 4 + pi]) | ((uint32_t)f2b(rf[5 * 4 + pi]) << 16);
        o.w = (uint32_t)f2b(rf[6 * 4 + pi]) | ((uint32_t)f2b(rf[7 * 4 + pi]) << 16);
        *(uint4*)&As[0][(pxq * 4 + pi) * 64 + cb * 8] = o;
    }
    __syncthreads();
    int cur = 0;
#pragma unroll
    for (int kt = 64; kt < 256; kt += 64) {
#pragma unroll
        for (int j = 0; j < 8; ++j)
            rg[j] = *(const uint4*)(aptr + (size_t)(kt + j) * 16384);
        stage_tile(wb + kt * 2, 512, Ws[cur ^ 1], wave, lane);
        compute64(As[cur], Ws[cur], wm, wn, l16, q, acc);
#pragma unroll
        for (int pi = 0; pi < 4; ++pi) {
            const float* rf = (const float*)rg;
            uint4 o;
            o.x = (uint32_t)f2b(rf[0 * 4 + pi]) | ((uint32_t)f2b(rf[1 * 4 + pi]) << 16);
            o.y = (uint32_t)f2b(rf[2 * 4 + pi]) | ((uint32_t)f2b(rf[3 * 4 + pi]) << 16);
            o.z = (uint32_t)f2b(rf[4 * 4 + pi]) | ((uint32_t)f2b(rf[5 * 4 + pi]) << 16);
            o.w = (uint32_t)f2b(rf[6 * 4 + pi]) | ((uint32_t)f2b(rf[7 * 4 + pi]) << 16);
            *(uint4*)&As[cur ^ 1][(pxq * 4 + pi) * 64 + cb * 8] = o;
        }
        __syncthreads();
        cur ^= 1;
    }
    compute64(As[cur], Ws[cur], wm, wn, l16, q, acc);

    // ---- epilogue: stage gather rows in LDS (buffers [0]; final compute used [1]) ----
    u16* g1s = &As[0][0];
    u16* g2s = &Ws[0][0];
    u16* g3s = &Ws[0][0] + 4096;
    float* pecs = (float*)(&Ws[0][0] + 6144);
    {
        const u16* g1p = G1 + ((size_t)(b * 4096 + (iy >> 1) * 64)) * 512 + n0;
#pragma unroll
        for (int it = 0; it < 4; ++it) {
            int u = it * 256 + tid;
            int row = u >> 4, c8 = u & 15;
            *(uint4*)&g1s[row * 128 + c8 * 8] = *(const uint4*)&g1p[(size_t)row * 512 + c8 * 8];
        }
        const u16* g2p = G2 + ((size_t)(b * 1024 + (iy >> 2) * 32)) * 512 + n0;
#pragma unroll
        for (int it = 0; it < 2; ++it) {
            int u = it * 256 + tid;
            int row = u >> 4, c8 = u & 15;
            *(uint4*)&g2s[row * 128 + c8 * 8] = *(const uint4*)&g2p[(size_t)row * 512 + c8 * 8];
        }
        const u16* g3p = G3 + ((size_t)(b * 256 + (iy >> 3) * 16)) * 512 + n0;
        {
            int row = tid >> 4, c8 = tid & 15;
            *(uint4*)&g3s[row * 128 + c8 * 8] = *(const uint4*)&g3p[(size_t)row * 512 + c8 * 8];
        }
        const float* pp = pec + (size_t)((iy & 7) * 8) * 512 + n0;
        {
            int row = tid >> 5, c4 = tid & 31;
            *(uint4*)&pecs[row * 128 + c4 * 4] = *(const uint4*)&pp[(size_t)row * 512 + c4 * 4];
        }
    }
    __syncthreads();
    float s1[4] = {0.f, 0.f, 0.f, 0.f}, s2[4] = {0.f, 0.f, 0.f, 0.f};
#pragma unroll
    for (int mi = 0; mi < 4; ++mi) {
#pragma unroll
        for (int r = 0; r < 4; ++r) {
            int ix = wm * 64 + mi * 16 + q * 4 + r;
#pragma unroll
            for (int ni = 0; ni < 4; ++ni) {
                int nl = wn * 64 + ni * 16 + l16;
                float v = acc[mi][ni][r]
                        + b2f(g1s[(ix >> 1) * 128 + nl])
                        + b2f(g2s[(ix >> 2) * 128 + nl])
                        + b2f(g3s[(ix >> 3) * 128 + nl])
                        + pecs[(ix & 7) * 128 + nl];
                Y[(size_t)(m0 + ix) * 512 + (n0 + nl)] = f2b(v);
                s1[ni] += v;
                s2[ni] += v * v;
            }
        }
    }
#pragma unroll
    for (int ni = 0; ni < 4; ++ni) {
        float a = s1[ni], bq = s2[ni];
        a += __shfl_xor(a, 16); a += __shfl_xor(a, 32);
        bq += __shfl_xor(bq, 16); bq += __shfl_xor(bq, 32);
        if (q == 0) {
            int n = n0 + wn * 64 + ni * 16 + l16;
            atomicAdd(&stats[n], a);
            atomicAdd(&stats[512 + n], bq);
        }
    }
}

// ---------------- BN finalize ----------------
__global__ void finalize_bn(const float* __restrict__ stats, const float* __restrict__ g,
                            const float* __restrict__ be, float* __restrict__ bnp, int N) {
    int n = blockIdx.x * blockDim.x + threadIdx.x;
    if (n >= N) return;
    float inv = 1.0f / (float)MTOT;
    float mean = stats[n] * inv;
    float var = stats[N + n] * inv - mean * mean;
    float sc = g[n] * rsqrtf(var + 1e-5f);
    bnp[n] = sc;
    bnp[N + n] = be[n] - mean * sc;
}

// ---------------- final: BN3+ReLU fused 256 -> 19 conv ----------------
__global__ __launch_bounds__(256) void gemm4_out(const u16* __restrict__ Y3,
                                                 const float* __restrict__ w4,
                                                 const float* __restrict__ b4,
                                                 const float* __restrict__ bnp3,
                                                 float* __restrict__ out) {
    __shared__ float w4s[19 * 256];
    int t = threadIdx.x;
    for (int i = t; i < 19 * 256; i += 256) w4s[i] = w4[i];
    __syncthreads();
    int mloc = t >> 4, l16 = t & 15;
    int m = blockIdx.x * 16 + mloc;
    float sc[16], sh[16];
#pragma unroll
    for (int j = 0; j < 16; ++j) {
        sc[j] = bnp3[l16 * 16 + j];
        sh[j] = bnp3[256 + l16 * 16 + j];
    }
    const uint4* yp = (const uint4*)((const char*)Y3 + (size_t)m * 512 + l16 * 32);
    uint4 v0 = yp[0], v1 = yp[1];
    uint32_t uu[8] = {v0.x, v0.y, v0.z, v0.w, v1.x, v1.y, v1.z, v1.w};
    float y[16];
#pragma unroll
    for (int p = 0; p < 8; ++p) {
        y[p * 2]     = __uint_as_float(uu[p] << 16);
        y[p * 2 + 1] = __uint_as_float(uu[p] & 0xffff0000u);
    }
#pragma unroll
    for (int j = 0; j < 16; ++j) y[j] = fmaxf(y[j] * sc[j] + sh[j], 0.f);
    float accv[19];
#pragma unroll
    for (int c = 0; c < 19; ++c) {
        const float* wr = &w4s[c * 256 + l16 * 16];
        float s = 0.f;
#pragma unroll
        for (int j = 0; j < 16; ++j) s += y[j] * wr[j];
        accv[c] = s;
    }
#pragma unroll
    for (int c = 0; c < 19; ++c) {
        float s = accv[c];
        s += __shfl_xor(s, 8, 16);
        s += __shfl_xor(s, 4, 16);
        s += __shfl_xor(s, 2, 16);
        s += __shfl_xor(s, 1, 16);
        accv[c] = s;
    }
    if (l16 == 0) {
        int b = m >> 14, l = m & 16383;
#pragma unroll
        for (int c = 0; c < 19; ++c)
            out[((size_t)b * 19 + c) * 16384 + l] = accv[c] + b4[c];
    }
}

extern "C" void kernel_launch(void* const* d_in, const int* in_sizes, int n_in,
                              void* d_out, int out_size, void* d_ws, size_t ws_size,
                              hipStream_t stream) {
    const float* x1 = (const float*)d_in[0];
    const float* x2 = (const float*)d_in[1];
    const float* x3 = (const float*)d_in[2];
    const float* x4 = (const float*)d_in[3];
    const float* w1 = (const float*)d_in[4];
    const float* b1 = (const float*)d_in[5];
    const float* g1 = (const float*)d_in[6];
    const float* be1 = (const float*)d_in[7];
    const float* w2 = (const float*)d_in[8];
    const float* b2 = (const float*)d_in[9];
    const float* g2 = (const float*)d_in[10];
    const float* be2 = (const float*)d_in[11];
    const float* w3 = (const float*)d_in[12];
    const float* b3 = (const float*)d_in[13];
    const float* g3 = (const float*)d_in[14];
    const float* be3 = (const float*)d_in[15];
    const float* w4 = (const float*)d_in[16];
    const float* b4 = (const float*)d_in[17];

    char* ws = (char*)d_ws;
    u16* Y3  = (u16*)(ws + 0);            // [65536][256]
    u16* A1  = (u16*)(ws + 33554432);     // [16384][256]
    u16* A2  = (u16*)(ws + 41943040);     // [4096][256]
    u16* A3  = (u16*)(ws + 44040192);     // [1024][256]
    u16* G1  = (u16*)(ws + 44564480);     // [16384][512]
    u16* G2  = (u16*)(ws + 61341696);     // [4096][512]
    u16* G3  = (u16*)(ws + 65536000);     // [1024][512]
    u16* Y2  = (u16*)(ws + 33554432);     // [65536][256] reuses A1..G3 region
    u16* Y1  = (u16*)(ws + 67108864);     // [65536][512]
    u16* wb1f = (u16*)(ws + 134217728);   // [4][512][256]
    u16* wb2 = (u16*)(ws + 135266304);    // [256][512]
    u16* wb3 = (u16*)(ws + 135528448);    // [256][256]
    float* pec = (float*)(ws + 135659520);// [64][512] f32
    float* stats = (float*)(ws + 135790592);
    float* bnp   = (float*)(ws + 135802880);

    zero_stats<<<12, 256, 0, stream>>>(stats);
    build_pec<<<64, 512, 0, stream>>>(w1, b1, pec);
    cvt_w1f<<<512, 256, 0, stream>>>(w1, wb1f);
    cvt_flat<<<256, 256, 0, stream>>>(w2, wb2, 256 * 512);
    cvt_flat<<<128, 256, 0, stream>>>(w3, wb3, 256 * 256);

    cvt_tr<<<256, 256, 0, stream>>>(x2, A1, 12);
    cvt_tr<<<64, 256, 0, stream>>>(x3, A2, 10);
    cvt_tr<<<16, 256, 0, stream>>>(x4, A3, 8);
    gemm_levels<<<dim3(4, 168), 256, 0, stream>>>(wb1f, A1, A2, A3, G1, G2, G3);

    // layer 1: x1 transpose fused into GEMM A-staging (A0 buffer eliminated)
    gemm_f1x<<<dim3(4, 512), 256, 0, stream>>>(wb1f, x1, G1, G2, G3, pec, Y1, stats);
    finalize_bn<<<2, 256, 0, stream>>>(stats, g1, be1, bnp, 512);

    gemm_bn<<<dim3(2, 512), 256, 0, stream>>>(wb2, Y1, bnp, bnp + 512, b2, Y2,
                                              stats + 1024, 256, 512);
    finalize_bn<<<1, 256, 0, stream>>>(stats + 1024, g2, be2, bnp + 1024, 256);

    gemm_bn<<<dim3(2, 512), 256, 0, stream>>>(wb3, Y2, bnp + 1024, bnp + 1024 + 256, b3, Y3,
                                              stats + 2048, 256, 256);
    finalize_bn<<<1, 256, 0, stream>>>(stats + 2048, g3, be3, bnp + 2048, 256);

    gemm4_out<<<4096, 256, 0, stream>>>(Y3, w4, b4, bnp + 2048, (float*)d_out);
}

// Round 7
// 261.848 us; speedup vs baseline: 1.2170x; 1.0812x over previous
//
#include <hip/hip_runtime.h>
#include <hip/hip_bf16.h>
#include <stdint.h>

typedef unsigned short u16;
typedef __bf16 bf16x8 __attribute__((ext_vector_type(8)));
typedef float f32x4 __attribute__((ext_vector_type(4)));

#define MTOT 65536

__device__ __forceinline__ u16 f2b(float f) {
    uint32_t u = __float_as_uint(f);
    u += 0x7fffu + ((u >> 16) & 1u);
    return (u16)(u >> 16);
}
__device__ __forceinline__ float b2f(u16 h) {
    return __uint_as_float(((uint32_t)h) << 16);
}

// packed f32x2 -> bf16x2 (RNE), single instruction (m240 recipe)
__device__ __forceinline__ uint32_t pk2(float a, float b) {
    uint32_t r;
    asm("v_cvt_pk_bf16_f32 %0, %1, %2" : "=v"(r) : "v"(a), "v"(b));
    return r;
}

// LDS 16B-chunk swizzle: chunk c of row r lives at slot c ^ swz8(r). Uniform
// 8-lanes/slot on every access pattern used below => conflict-free b128 ops.
__device__ __forceinline__ int swz8(int r) { return (r ^ (r >> 3)) & 7; }

__device__ __forceinline__ void gload16(const void* g, void* l) {
    __builtin_amdgcn_global_load_lds((const __attribute__((address_space(1))) void*)g,
                                     (__attribute__((address_space(3))) void*)l, 16, 0, 0);
}

// stage one 128x64 bf16 tile via global_load_lds; LDS dest linear, SOURCE column
// pre-swizzled per-lane so content lands at slot c ^ swz8(r) (m173 pattern).
__device__ __forceinline__ void stage_tile(const char* gbase, size_t ldb,
                                           u16* lbuf, int wave, int lane) {
    int lr = lane >> 3, lc = lane & 7;
#pragma unroll
    for (int i = 0; i < 4; ++i) {
        int r = wave * 32 + i * 8 + lr;
        int csrc = lc ^ swz8(r);
        gload16(gbase + (size_t)r * ldb + csrc * 16, lbuf + (wave * 32 + i * 8) * 64);
    }
}

// swizzle-aware MFMA step over a 64-wide K slab
__device__ __forceinline__ void compute64(const u16* As, const u16* Ws, int wm, int wn,
                                          int l16, int q, f32x4 (&acc)[4][4]) {
#pragma unroll
    for (int kk = 0; kk < 64; kk += 32) {
        int c0 = (kk >> 3) + q;
        bf16x8 af[4], wf[4];
#pragma unroll
        for (int mi = 0; mi < 4; ++mi) {
            int r = wm * 64 + mi * 16 + l16;
            af[mi] = *(const bf16x8*)&As[r * 64 + ((c0 ^ swz8(r)) << 3)];
        }
#pragma unroll
        for (int ni = 0; ni < 4; ++ni) {
            int r = wn * 64 + ni * 16 + l16;
            wf[ni] = *(const bf16x8*)&Ws[r * 64 + ((c0 ^ swz8(r)) << 3)];
        }
#pragma unroll
        for (int mi = 0; mi < 4; ++mi)
#pragma unroll
            for (int ni = 0; ni < 4; ++ni)
                acc[mi][ni] = __builtin_amdgcn_mfma_f32_16x16x32_bf16(af[mi], wf[ni], acc[mi][ni], 0, 0, 0);
    }
}

// load 8ch x 4px f32 block for one thread (A-tile from [ch][px]-layout f32 input)
__device__ __forceinline__ void load_a(const float* xb, size_t plane, int tid, uint4 (&rg)[8]) {
    int pxq = tid & 31, cb = tid >> 5;
    const float* aptr = xb + (size_t)(cb * 8) * plane + pxq * 4;
#pragma unroll
    for (int j = 0; j < 8; ++j)
        rg[j] = *(const uint4*)(aptr + (size_t)j * plane);
}
// convert + swizzled LDS write ([px][ch] bf16, slot-swizzled)
__device__ __forceinline__ void write_a(const uint4 (&rg)[8], u16* lbuf, int tid) {
    int pxq = tid & 31, cb = tid >> 5;
    const float* rf = (const float*)rg;
#pragma unroll
    for (int pi = 0; pi < 4; ++pi) {
        uint4 o;
        o.x = pk2(rf[0 + pi], rf[4 + pi]);
        o.y = pk2(rf[8 + pi], rf[12 + pi]);
        o.z = pk2(rf[16 + pi], rf[20 + pi]);
        o.w = pk2(rf[24 + pi], rf[28 + pi]);
        int r = pxq * 4 + pi;
        *(uint4*)&lbuf[r * 64 + ((cb ^ swz8(r)) << 3)] = o;
    }
}

// BN+ReLU on 8 bf16 channels in a uint4
__device__ __forceinline__ uint4 bn8(uint4 v, const float* __restrict__ sc,
                                     const float* __restrict__ sh) {
    float f[8];
    const uint32_t* w = (const uint32_t*)&v;
#pragma unroll
    for (int p = 0; p < 4; ++p) {
        f[2 * p]     = fmaxf(__uint_as_float(w[p] << 16) * sc[2 * p] + sh[2 * p], 0.f);
        f[2 * p + 1] = fmaxf(__uint_as_float(w[p] & 0xffff0000u) * sc[2 * p + 1] + sh[2 * p + 1], 0.f);
    }
    uint4 r;
    r.x = pk2(f[0], f[1]); r.y = pk2(f[2], f[3]);
    r.z = pk2(f[4], f[5]); r.w = pk2(f[6], f[7]);
    return r;
}

// block remap: n-siblings of one m-tile land on the SAME XCD, adjacent in time.
template <int GX>
__device__ __forceinline__ void remap(int& bx, int& by) {
    int f = blockIdx.y * GX + blockIdx.x;
    int r = f & 7, s = f >> 3;
    bx = s % GX;
    by = r + (s / GX) * 8;
}

// XCD-aware bijective swizzle (nwg % 8 == 0 required)
__device__ __forceinline__ int xcd_swz(int flat, int nwg) {
    int chunk = nwg >> 3;
    return (flat & 7) * chunk + (flat >> 3);
}

// ---------------- zero stats ----------------
__global__ void zero_stats(float* __restrict__ p) {
    int i = blockIdx.x * 256 + threadIdx.x;
    if (i < 3072) p[i] = 0.f;
}

// ---------------- PE table: PEC[(dy*8+dx)][n] ----------------
__global__ __launch_bounds__(512) void build_pec(const float* __restrict__ w1,
                                                 const float* __restrict__ b1,
                                                 float* __restrict__ pec) {
    __shared__ float pe[168];
    int dy = blockIdx.x >> 3, dx = blockIdx.x & 7;
    int t = threadIdx.x;
    if (t < 168) {
        int lv = t / 42, j = t - lv * 42;
        int msk = (1 << lv) - 1;
        float inv = 1.0f / (float)(1 << lv);
        float ry = (float)(2 * (dy & msk) + 1) * inv - 1.0f;
        float rx = (float)(2 * (dx & msk) + 1) * inv - 1.0f;
        float v;
        if (j == 0) v = ry;
        else if (j == 1) v = rx;
        else if (j < 12)  v = sinf(exp2f((float)(j - 2)  * (2.0f/3.0f)) * ry);
        else if (j < 22)  v = sinf(exp2f((float)(j - 12) * (2.0f/3.0f)) * rx);
        else if (j < 32)  v = cosf(exp2f((float)(j - 22) * (2.0f/3.0f)) * ry);
        else              v = cosf(exp2f((float)(j - 32) * (2.0f/3.0f)) * rx);
        pe[t] = v;
    }
    __syncthreads();
    int n = t;
    float acc = b1[n];
#pragma unroll 4
    for (int lv = 0; lv < 4; ++lv)
        for (int j = 0; j < 42; ++j)
            acc += pe[lv * 42 + j] * w1[n * 1192 + lv * 298 + j];
    pec[(size_t)blockIdx.x * 512 + n] = acc;
}

// ---------------- W1 feature-part extract ----------------
__global__ void cvt_w1f(const float* __restrict__ w1, u16* __restrict__ dst) {
    for (int i = blockIdx.x * 256 + threadIdx.x; i < 4 * 512 * 256; i += gridDim.x * 256) {
        int lv = i >> 17;
        int rem = i & 131071;
        int n = rem >> 8, c = rem & 255;
        dst[i] = f2b(w1[n * 1192 + lv * 298 + 42 + c]);
    }
}

// ---------------- flat f32 -> bf16 ----------------
__global__ void cvt_flat(const float* __restrict__ src, u16* __restrict__ dst, int total) {
    for (int i = blockIdx.x * 256 + threadIdx.x; i < total; i += gridDim.x * 256)
        dst[i] = f2b(src[i]);
}

// ---------------- fused BN+ReLU(A) GEMM ----------------
__global__ __launch_bounds__(256) void gemm_bn(const u16* __restrict__ W,
                                               const u16* __restrict__ Act,
                                               const float* __restrict__ scale,
                                               const float* __restrict__ shift,
                                               const float* __restrict__ bias,
                                               u16* __restrict__ Y,
                                               float* __restrict__ stats, int N, int K) {
    __shared__ u16 As[2][8192];
    __shared__ u16 Ws[2][8192];
    int tid = threadIdx.x;
    int wave = tid >> 6, lane = tid & 63;
    int wm = wave >> 1, wn = wave & 1;
    int bx, by;
    remap<2>(bx, by);
    int n0 = bx * 128, m0 = by * 128;
    int q = lane >> 4, l16 = lane & 15;
    f32x4 acc[4][4];
#pragma unroll
    for (int i = 0; i < 4; ++i)
#pragma unroll
        for (int j = 0; j < 4; ++j) acc[i][j] = {0.f, 0.f, 0.f, 0.f};
    int lr = lane >> 3, ch = lane & 7;
    size_t ldb = (size_t)K * 2;
    const char* actb = (const char*)Act + (size_t)m0 * ldb + ch * 16;
    const char* wb = (const char*)W + (size_t)n0 * ldb;
    uint4 rg[4];
#pragma unroll
    for (int i = 0; i < 4; ++i)
        rg[i] = *(const uint4*)(actb + (size_t)(wave * 32 + i * 8 + lr) * ldb);
    stage_tile(wb, ldb, Ws[0], wave, lane);
    {
        const float* sc = scale + ch * 8;
        const float* sh = shift + ch * 8;
#pragma unroll
        for (int i = 0; i < 4; ++i) {
            int r = wave * 32 + i * 8 + lr;
            *(uint4*)&As[0][r * 64 + ((ch ^ swz8(r)) << 3)] = bn8(rg[i], sc, sh);
        }
    }
    __syncthreads();
    int cur = 0;
    for (int kt = 64; kt < K; kt += 64) {
#pragma unroll
        for (int i = 0; i < 4; ++i)
            rg[i] = *(const uint4*)(actb + (size_t)(wave * 32 + i * 8 + lr) * ldb + kt * 2);
        stage_tile(wb + kt * 2, ldb, Ws[cur ^ 1], wave, lane);
        compute64(As[cur], Ws[cur], wm, wn, l16, q, acc);
        const float* sc = scale + kt + ch * 8;
        const float* sh = shift + kt + ch * 8;
#pragma unroll
        for (int i = 0; i < 4; ++i) {
            int r = wave * 32 + i * 8 + lr;
            *(uint4*)&As[cur ^ 1][r * 64 + ((ch ^ swz8(r)) << 3)] = bn8(rg[i], sc, sh);
        }
        __syncthreads();
        cur ^= 1;
    }
    compute64(As[cur], Ws[cur], wm, wn, l16, q, acc);

    float bv[4];
#pragma unroll
    for (int ni = 0; ni < 4; ++ni)
        bv[ni] = bias[n0 + wn * 64 + ni * 16 + l16];
    float s1[4] = {0.f, 0.f, 0.f, 0.f}, s2[4] = {0.f, 0.f, 0.f, 0.f};
#pragma unroll
    for (int mi = 0; mi < 4; ++mi) {
#pragma unroll
        for (int r = 0; r < 4; ++r) {
            int m = m0 + wm * 64 + mi * 16 + q * 4 + r;
#pragma unroll
            for (int ni = 0; ni < 4; ++ni) {
                float v = acc[mi][ni][r] + bv[ni];
                Y[(size_t)m * N + (n0 + wn * 64 + ni * 16 + l16)] = f2b(v);
                s1[ni] += v;
                s2[ni] += v * v;
            }
        }
    }
    if (stats) {
#pragma unroll
        for (int ni = 0; ni < 4; ++ni) {
            float a = s1[ni], bq = s2[ni];
            a += __shfl_xor(a, 16); a += __shfl_xor(a, 32);
            bq += __shfl_xor(bq, 16); bq += __shfl_xor(bq, 32);
            if (q == 0) {
                int n = n0 + wn * 64 + ni * 16 + l16;
                atomicAdd(&stats[n], a);
                atomicAdd(&stats[N + n], bq);
            }
        }
    }
}

// ---------------- merged low-res level GEMMs, x-transpose fused into A-staging ----------------
// grid (4, 168): y<128 -> lv1 (x2, plane 4096), y<160 -> lv2 (x3, 1024), else lv3 (x4, 256)
__global__ __launch_bounds__(256) void gemm_levels(const u16* __restrict__ wb1f,
                                                   const float* __restrict__ x2,
                                                   const float* __restrict__ x3,
                                                   const float* __restrict__ x4,
                                                   u16* __restrict__ G1,
                                                   u16* __restrict__ G2,
                                                   u16* __restrict__ G3) {
    __shared__ u16 As[2][8192];
    __shared__ u16 Ws[2][8192];
    int tid = threadIdx.x;
    int wave = tid >> 6, lane = tid & 63;
    int wm = wave >> 1, wn = wave & 1;
    int swz = xcd_swz(blockIdx.y * 4 + blockIdx.x, 672);
    int bx = swz & 3, by = swz >> 2;
    const float* X; u16* G; const u16* W;
    int mt, s2;
    if (by < 128)      { X = x2; G = G1; W = wb1f + 1 * 131072; mt = by;       s2 = 12; }
    else if (by < 160) { X = x3; G = G2; W = wb1f + 2 * 131072; mt = by - 128; s2 = 10; }
    else               { X = x4; G = G3; W = wb1f + 3 * 131072; mt = by - 160; s2 = 8; }
    int n0 = bx * 128, m0 = mt * 128;
    size_t plane = (size_t)1 << s2;
    int b = m0 >> s2;
    int pxbase = m0 & ((1 << s2) - 1);
    const float* xb0 = X + ((size_t)b * 256) * plane + pxbase;
    int q = lane >> 4, l16 = lane & 15;
    f32x4 acc[4][4];
#pragma unroll
    for (int i = 0; i < 4; ++i)
#pragma unroll
        for (int j = 0; j < 4; ++j) acc[i][j] = {0.f, 0.f, 0.f, 0.f};
    const char* wb = (const char*)W + (size_t)n0 * 512;

    uint4 rg[8];
    load_a(xb0, plane, tid, rg);
    stage_tile(wb, 512, Ws[0], wave, lane);
    write_a(rg, As[0], tid);
    __syncthreads();
    int cur = 0;
#pragma unroll
    for (int kt = 64; kt < 256; kt += 64) {
        load_a(xb0 + (size_t)kt * plane, plane, tid, rg);
        stage_tile(wb + kt * 2, 512, Ws[cur ^ 1], wave, lane);
        compute64(As[cur], Ws[cur], wm, wn, l16, q, acc);
        write_a(rg, As[cur ^ 1], tid);
        __syncthreads();
        cur ^= 1;
    }
    compute64(As[cur], Ws[cur], wm, wn, l16, q, acc);

#pragma unroll
    for (int mi = 0; mi < 4; ++mi)
#pragma unroll
        for (int r = 0; r < 4; ++r) {
            int m = m0 + wm * 64 + mi * 16 + q * 4 + r;
#pragma unroll
            for (int ni = 0; ni < 4; ++ni)
                G[(size_t)m * 512 + (n0 + wn * 64 + ni * 16 + l16)] = f2b(acc[mi][ni][r]);
        }
}

// ---------------- fused layer-1: x1 transpose-in-kernel GEMM + gathers + PEC + stats ----------------
__global__ __launch_bounds__(256) void gemm_f1x(const u16* __restrict__ W,
                                                const float* __restrict__ x1,
                                                const u16* __restrict__ G1,
                                                const u16* __restrict__ G2,
                                                const u16* __restrict__ G3,
                                                const float* __restrict__ pec,
                                                u16* __restrict__ Y,
                                                float* __restrict__ stats) {
    __shared__ u16 As[2][8192];
    __shared__ u16 Ws[2][8192];
    int tid = threadIdx.x;
    int wave = tid >> 6, lane = tid & 63;
    int wm = wave >> 1, wn = wave & 1;
    int bx, by;
    remap<4>(bx, by);
    int n0 = bx * 128, m0 = by * 128;
    int q = lane >> 4, l16 = lane & 15;
    f32x4 acc[4][4];
#pragma unroll
    for (int i = 0; i < 4; ++i)
#pragma unroll
        for (int j = 0; j < 4; ++j) acc[i][j] = {0.f, 0.f, 0.f, 0.f};
    int b = m0 >> 14;
    int iy = (m0 >> 7) & 127;
    const float* xb0 = x1 + ((size_t)b * 256) * 16384 + (size_t)iy * 128;
    const char* wb = (const char*)W + (size_t)n0 * 512;

    uint4 rg[8];
    load_a(xb0, 16384, tid, rg);
    stage_tile(wb, 512, Ws[0], wave, lane);
    write_a(rg, As[0], tid);
    __syncthreads();
    int cur = 0;
#pragma unroll
    for (int kt = 64; kt < 256; kt += 64) {
        load_a(xb0 + (size_t)kt * 16384, 16384, tid, rg);
        stage_tile(wb + kt * 2, 512, Ws[cur ^ 1], wave, lane);
        compute64(As[cur], Ws[cur], wm, wn, l16, q, acc);
        write_a(rg, As[cur ^ 1], tid);
        __syncthreads();
        cur ^= 1;
    }
    compute64(As[cur], Ws[cur], wm, wn, l16, q, acc);

    // ---- epilogue: stage gather rows in LDS (linear reuse of As/Ws) ----
    u16* g1s = &As[0][0];
    u16* g2s = &Ws[0][0];
    u16* g3s = &Ws[0][0] + 4096;
    float* pecs = (float*)(&Ws[0][0] + 6144);
    {
        const u16* g1p = G1 + ((size_t)(b * 4096 + (iy >> 1) * 64)) * 512 + n0;
#pragma unroll
        for (int it = 0; it < 4; ++it) {
            int u = it * 256 + tid;
            int row = u >> 4, c8 = u & 15;
            *(uint4*)&g1s[row * 128 + c8 * 8] = *(const uint4*)&g1p[(size_t)row * 512 + c8 * 8];
        }
        const u16* g2p = G2 + ((size_t)(b * 1024 + (iy >> 2) * 32)) * 512 + n0;
#pragma unroll
        for (int it = 0; it < 2; ++it) {
            int u = it * 256 + tid;
            int row = u >> 4, c8 = u & 15;
            *(uint4*)&g2s[row * 128 + c8 * 8] = *(const uint4*)&g2p[(size_t)row * 512 + c8 * 8];
        }
        const u16* g3p = G3 + ((size_t)(b * 256 + (iy >> 3) * 16)) * 512 + n0;
        {
            int row = tid >> 4, c8 = tid & 15;
            *(uint4*)&g3s[row * 128 + c8 * 8] = *(const uint4*)&g3p[(size_t)row * 512 + c8 * 8];
        }
        const float* pp = pec + (size_t)((iy & 7) * 8) * 512 + n0;
        {
            int row = tid >> 5, c4 = tid & 31;
            *(uint4*)&pecs[row * 128 + c4 * 4] = *(const uint4*)&pp[(size_t)row * 512 + c4 * 4];
        }
    }
    __syncthreads();
    float s1[4] = {0.f, 0.f, 0.f, 0.f}, s2[4] = {0.f, 0.f, 0.f, 0.f};
#pragma unroll
    for (int mi = 0; mi < 4; ++mi) {
#pragma unroll
        for (int r = 0; r < 4; ++r) {
            int ix = wm * 64 + mi * 16 + q * 4 + r;
#pragma unroll
            for (int ni = 0; ni < 4; ++ni) {
                int nl = wn * 64 + ni * 16 + l16;
                float v = acc[mi][ni][r]
                        + b2f(g1s[(ix >> 1) * 128 + nl])
                        + b2f(g2s[(ix >> 2) * 128 + nl])
                        + b2f(g3s[(ix >> 3) * 128 + nl])
                        + pecs[(ix & 7) * 128 + nl];
                Y[(size_t)(m0 + ix) * 512 + (n0 + nl)] = f2b(v);
                s1[ni] += v;
                s2[ni] += v * v;
            }
        }
    }
#pragma unroll
    for (int ni = 0; ni < 4; ++ni) {
        float a = s1[ni], bq = s2[ni];
        a += __shfl_xor(a, 16); a += __shfl_xor(a, 32);
        bq += __shfl_xor(bq, 16); bq += __shfl_xor(bq, 32);
        if (q == 0) {
            int n = n0 + wn * 64 + ni * 16 + l16;
            atomicAdd(&stats[n], a);
            atomicAdd(&stats[512 + n], bq);
        }
    }
}

// ---------------- BN finalize ----------------
__global__ void finalize_bn(const float* __restrict__ stats, const float* __restrict__ g,
                            const float* __restrict__ be, float* __restrict__ bnp, int N) {
    int n = blockIdx.x * blockDim.x + threadIdx.x;
    if (n >= N) return;
    float inv = 1.0f / (float)MTOT;
    float mean = stats[n] * inv;
    float var = stats[N + n] * inv - mean * mean;
    float sc = g[n] * rsqrtf(var + 1e-5f);
    bnp[n] = sc;
    bnp[N + n] = be[n] - mean * sc;
}

// ---------------- final: BN3+ReLU fused 256 -> 19 conv (grid-stride) ----------------
__global__ __launch_bounds__(256) void gemm4_out(const u16* __restrict__ Y3,
                                                 const float* __restrict__ w4,
                                                 const float* __restrict__ b4,
                                                 const float* __restrict__ bnp3,
                                                 float* __restrict__ out) {
    __shared__ float w4s[19 * 256];
    int t = threadIdx.x;
    for (int i = t; i < 19 * 256; i += 256) w4s[i] = w4[i];
    __syncthreads();
    int mloc = t >> 4, l16 = t & 15;
    float sc[16], sh[16];
#pragma unroll
    for (int j = 0; j < 16; ++j) {
        sc[j] = bnp3[l16 * 16 + j];
        sh[j] = bnp3[256 + l16 * 16 + j];
    }
    for (int mt = blockIdx.x; mt < 4096; mt += gridDim.x) {
        int m = mt * 16 + mloc;
        const uint4* yp = (const uint4*)((const char*)Y3 + (size_t)m * 512 + l16 * 32);
        uint4 v0 = yp[0], v1 = yp[1];
        uint32_t uu[8] = {v0.x, v0.y, v0.z, v0.w, v1.x, v1.y, v1.z, v1.w};
        float y[16];
#pragma unroll
        for (int p = 0; p < 8; ++p) {
            y[p * 2]     = __uint_as_float(uu[p] << 16);
            y[p * 2 + 1] = __uint_as_float(uu[p] & 0xffff0000u);
        }
#pragma unroll
        for (int j = 0; j < 16; ++j) y[j] = fmaxf(y[j] * sc[j] + sh[j], 0.f);
        float accv[19];
#pragma unroll
        for (int c = 0; c < 19; ++c) {
            const float* wr = &w4s[c * 256 + l16 * 16];
            float s = 0.f;
#pragma unroll
            for (int j = 0; j < 16; ++j) s += y[j] * wr[j];
            accv[c] = s;
        }
#pragma unroll
        for (int c = 0; c < 19; ++c) {
            float s = accv[c];
            s += __shfl_xor(s, 8, 16);
            s += __shfl_xor(s, 4, 16);
            s += __shfl_xor(s, 2, 16);
            s += __shfl_xor(s, 1, 16);
            accv[c] = s;
        }
        if (l16 == 0) {
            int b = m >> 14, l = m & 16383;
#pragma unroll
            for (int c = 0; c < 19; ++c)
                out[((size_t)b * 19 + c) * 16384 + l] = accv[c] + b4[c];
        }
    }
}

extern "C" void kernel_launch(void* const* d_in, const int* in_sizes, int n_in,
                              void* d_out, int out_size, void* d_ws, size_t ws_size,
                              hipStream_t stream) {
    const float* x1 = (const float*)d_in[0];
    const float* x2 = (const float*)d_in[1];
    const float* x3 = (const float*)d_in[2];
    const float* x4 = (const float*)d_in[3];
    const float* w1 = (const float*)d_in[4];
    const float* b1 = (const float*)d_in[5];
    const float* g1 = (const float*)d_in[6];
    const float* be1 = (const float*)d_in[7];
    const float* w2 = (const float*)d_in[8];
    const float* b2 = (const float*)d_in[9];
    const float* g2 = (const float*)d_in[10];
    const float* be2 = (const float*)d_in[11];
    const float* w3 = (const float*)d_in[12];
    const float* b3 = (const float*)d_in[13];
    const float* g3 = (const float*)d_in[14];
    const float* be3 = (const float*)d_in[15];
    const float* w4 = (const float*)d_in[16];
    const float* b4 = (const float*)d_in[17];

    char* ws = (char*)d_ws;
    u16* Y3  = (u16*)(ws + 0);            // [65536][256]
    u16* G1  = (u16*)(ws + 44564480);     // [16384][512]
    u16* G2  = (u16*)(ws + 61341696);     // [4096][512]
    u16* G3  = (u16*)(ws + 65536000);     // [1024][512]
    u16* Y2  = (u16*)(ws + 33554432);     // [65536][256]
    u16* Y1  = (u16*)(ws + 67108864);     // [65536][512]
    u16* wb1f = (u16*)(ws + 134217728);   // [4][512][256]
    u16* wb2 = (u16*)(ws + 135266304);    // [256][512]
    u16* wb3 = (u16*)(ws + 135528448);    // [256][256]
    float* pec = (float*)(ws + 135659520);// [64][512] f32
    float* stats = (float*)(ws + 135790592);
    float* bnp   = (float*)(ws + 135802880);

    zero_stats<<<12, 256, 0, stream>>>(stats);
    build_pec<<<64, 512, 0, stream>>>(w1, b1, pec);
    cvt_w1f<<<512, 256, 0, stream>>>(w1, wb1f);
    cvt_flat<<<256, 256, 0, stream>>>(w2, wb2, 256 * 512);
    cvt_flat<<<128, 256, 0, stream>>>(w3, wb3, 256 * 256);

    // low-res levels: x-transpose fused into A-staging
    gemm_levels<<<dim3(4, 168), 256, 0, stream>>>(wb1f, x2, x3, x4, G1, G2, G3);

    // layer 1: x1 transpose fused into GEMM A-staging
    gemm_f1x<<<dim3(4, 512), 256, 0, stream>>>(wb1f, x1, G1, G2, G3, pec, Y1, stats);
    finalize_bn<<<2, 256, 0, stream>>>(stats, g1, be1, bnp, 512);

    gemm_bn<<<dim3(2, 512), 256, 0, stream>>>(wb2, Y1, bnp, bnp + 512, b2, Y2,
                                              stats + 1024, 256, 512);
    finalize_bn<<<1, 256, 0, stream>>>(stats + 1024, g2, be2, bnp + 1024, 256);

    gemm_bn<<<dim3(2, 512), 256, 0, stream>>>(wb3, Y2, bnp + 1024, bnp + 1024 + 256, b3, Y3,
                                              stats + 2048, 256, 256);
    finalize_bn<<<1, 256, 0, stream>>>(stats + 2048, g3, be3, bnp + 2048, 256);

    gemm4_out<<<512, 256, 0, stream>>>(Y3, w4, b4, bnp + 2048, (float*)d_out);
}

// Round 8
// 238.311 us; speedup vs baseline: 1.3372x; 1.0988x over previous
//
#include <hip/hip_runtime.h>
#include <hip/hip_bf16.h>
#include <stdint.h>

typedef unsigned short u16;
typedef __bf16 bf16x8 __attribute__((ext_vector_type(8)));
typedef float f32x4 __attribute__((ext_vector_type(4)));

#define MTOT 65536

__device__ __forceinline__ u16 f2b(float f) {
    uint32_t u = __float_as_uint(f);
    u += 0x7fffu + ((u >> 16) & 1u);
    return (u16)(u >> 16);
}
__device__ __forceinline__ float b2f(u16 h) {
    return __uint_as_float(((uint32_t)h) << 16);
}

// packed f32x2 -> bf16x2 (RNE), single instruction
__device__ __forceinline__ uint32_t pk2(float a, float b) {
    uint32_t r;
    asm("v_cvt_pk_bf16_f32 %0, %1, %2" : "=v"(r) : "v"(a), "v"(b));
    return r;
}

// LDS 16B-chunk swizzle: chunk c of row r lives at slot c ^ swz8(r).
__device__ __forceinline__ int swz8(int r) { return (r ^ (r >> 3)) & 7; }

__device__ __forceinline__ void gload16(const void* g, void* l) {
    __builtin_amdgcn_global_load_lds((const __attribute__((address_space(1))) void*)g,
                                     (__attribute__((address_space(3))) void*)l, 16, 0, 0);
}

// stage one 128x64 bf16 tile via global_load_lds; LDS dest linear, SOURCE column
// pre-swizzled per-lane so content lands at slot c ^ swz8(r).
__device__ __forceinline__ void stage_tile(const char* gbase, size_t ldb,
                                           u16* lbuf, int wave, int lane) {
    int lr = lane >> 3, lc = lane & 7;
#pragma unroll
    for (int i = 0; i < 4; ++i) {
        int r = wave * 32 + i * 8 + lr;
        int csrc = lc ^ swz8(r);
        gload16(gbase + (size_t)r * ldb + csrc * 16, lbuf + (wave * 32 + i * 8) * 64);
    }
}

// swizzle-aware MFMA step over a 64-wide K slab
__device__ __forceinline__ void compute64(const u16* As, const u16* Ws, int wm, int wn,
                                          int l16, int q, f32x4 (&acc)[4][4]) {
#pragma unroll
    for (int kk = 0; kk < 64; kk += 32) {
        int c0 = (kk >> 3) + q;
        bf16x8 af[4], wf[4];
#pragma unroll
        for (int mi = 0; mi < 4; ++mi) {
            int r = wm * 64 + mi * 16 + l16;
            af[mi] = *(const bf16x8*)&As[r * 64 + ((c0 ^ swz8(r)) << 3)];
        }
#pragma unroll
        for (int ni = 0; ni < 4; ++ni) {
            int r = wn * 64 + ni * 16 + l16;
            wf[ni] = *(const bf16x8*)&Ws[r * 64 + ((c0 ^ swz8(r)) << 3)];
        }
#pragma unroll
        for (int mi = 0; mi < 4; ++mi)
#pragma unroll
            for (int ni = 0; ni < 4; ++ni)
                acc[mi][ni] = __builtin_amdgcn_mfma_f32_16x16x32_bf16(af[mi], wf[ni], acc[mi][ni], 0, 0, 0);
    }
}

// load 8ch x 4px f32 block for one thread
__device__ __forceinline__ void load_a(const float* xb, size_t plane, int tid, uint4 (&rg)[8]) {
    int pxq = tid & 31, cb = tid >> 5;
    const float* aptr = xb + (size_t)(cb * 8) * plane + pxq * 4;
#pragma unroll
    for (int j = 0; j < 8; ++j)
        rg[j] = *(const uint4*)(aptr + (size_t)j * plane);
}
// convert + swizzled LDS write ([px][ch] bf16, slot-swizzled)
__device__ __forceinline__ void write_a(const uint4 (&rg)[8], u16* lbuf, int tid) {
    int pxq = tid & 31, cb = tid >> 5;
    const float* rf = (const float*)rg;
#pragma unroll
    for (int pi = 0; pi < 4; ++pi) {
        uint4 o;
        o.x = pk2(rf[0 + pi], rf[4 + pi]);
        o.y = pk2(rf[8 + pi], rf[12 + pi]);
        o.z = pk2(rf[16 + pi], rf[20 + pi]);
        o.w = pk2(rf[24 + pi], rf[28 + pi]);
        int r = pxq * 4 + pi;
        *(uint4*)&lbuf[r * 64 + ((cb ^ swz8(r)) << 3)] = o;
    }
}

// BN+ReLU on 8 bf16 channels in a uint4 (scale/shift passed by value)
__device__ __forceinline__ uint4 bn8v(uint4 v, f32x4 s0, f32x4 s1, f32x4 h0, f32x4 h1) {
    float sa[8] = {s0[0], s0[1], s0[2], s0[3], s1[0], s1[1], s1[2], s1[3]};
    float ha[8] = {h0[0], h0[1], h0[2], h0[3], h1[0], h1[1], h1[2], h1[3]};
    const uint32_t* w = (const uint32_t*)&v;
    float f[8];
#pragma unroll
    for (int p = 0; p < 4; ++p) {
        f[2 * p]     = fmaxf(__uint_as_float(w[p] << 16) * sa[2 * p] + ha[2 * p], 0.f);
        f[2 * p + 1] = fmaxf(__uint_as_float(w[p] & 0xffff0000u) * sa[2 * p + 1] + ha[2 * p + 1], 0.f);
    }
    uint4 r;
    r.x = pk2(f[0], f[1]); r.y = pk2(f[2], f[3]);
    r.z = pk2(f[4], f[5]); r.w = pk2(f[6], f[7]);
    return r;
}

// block remap: n-siblings of one m-tile land on the SAME XCD, adjacent in time.
template <int GX>
__device__ __forceinline__ void remap(int& bx, int& by) {
    int f = blockIdx.y * GX + blockIdx.x;
    int r = f & 7, s = f >> 3;
    bx = s % GX;
    by = r + (s / GX) * 8;
}

// XCD-aware bijective swizzle (nwg % 8 == 0 required)
__device__ __forceinline__ int xcd_swz(int flat, int nwg) {
    int chunk = nwg >> 3;
    return (flat & 7) * chunk + (flat >> 3);
}

// ---------------- merged prep: PEC table + weight converts + stats zero ----------------
// 512 threads. blocks: [0,64) build_pec, [64,320) cvt_w1f, [320,384) w2, [384,416) w3, 416 zero.
__global__ __launch_bounds__(512) void prep(const float* __restrict__ w1,
                                            const float* __restrict__ b1,
                                            const float* __restrict__ w2,
                                            const float* __restrict__ w3,
                                            float* __restrict__ pec,
                                            u16* __restrict__ wb1f,
                                            u16* __restrict__ wb2,
                                            u16* __restrict__ wb3,
                                            float* __restrict__ stats) {
    int blk = blockIdx.x;
    int t = threadIdx.x;
    if (blk < 64) {
        __shared__ float pe[168];
        int dy = blk >> 3, dx = blk & 7;
        if (t < 168) {
            int lv = t / 42, j = t - lv * 42;
            int msk = (1 << lv) - 1;
            float inv = 1.0f / (float)(1 << lv);
            float ry = (float)(2 * (dy & msk) + 1) * inv - 1.0f;
            float rx = (float)(2 * (dx & msk) + 1) * inv - 1.0f;
            float v;
            if (j == 0) v = ry;
            else if (j == 1) v = rx;
            else if (j < 12)  v = sinf(exp2f((float)(j - 2)  * (2.0f/3.0f)) * ry);
            else if (j < 22)  v = sinf(exp2f((float)(j - 12) * (2.0f/3.0f)) * rx);
            else if (j < 32)  v = cosf(exp2f((float)(j - 22) * (2.0f/3.0f)) * ry);
            else              v = cosf(exp2f((float)(j - 32) * (2.0f/3.0f)) * rx);
            pe[t] = v;
        }
        __syncthreads();
        int n = t;
        float acc = b1[n];
#pragma unroll 4
        for (int lv = 0; lv < 4; ++lv)
            for (int j = 0; j < 42; ++j)
                acc += pe[lv * 42 + j] * w1[n * 1192 + lv * 298 + j];
        pec[(size_t)blk * 512 + n] = acc;
    } else if (blk < 320) {
        int i0 = (blk - 64) * 2048 + t;
#pragma unroll
        for (int j = 0; j < 4; ++j) {
            int i = i0 + j * 512;
            int lv = i >> 17;
            int rem = i & 131071;
            int n = rem >> 8, c = rem & 255;
            wb1f[i] = f2b(w1[n * 1192 + lv * 298 + 42 + c]);
        }
    } else if (blk < 384) {
        int i0 = (blk - 320) * 2048 + t;
#pragma unroll
        for (int j = 0; j < 4; ++j) {
            int i = i0 + j * 512;
            wb2[i] = f2b(w2[i]);
        }
    } else if (blk < 416) {
        int i0 = (blk - 384) * 2048 + t;
#pragma unroll
        for (int j = 0; j < 4; ++j) {
            int i = i0 + j * 512;
            wb3[i] = f2b(w3[i]);
        }
    } else {
        for (int i = t; i < 3072; i += 512) stats[i] = 0.f;
    }
}

// ---------------- fused BN+ReLU(A) GEMM with inline BN-finalize ----------------
__global__ __launch_bounds__(256) void gemm_bn(const u16* __restrict__ W,
                                               const u16* __restrict__ Act,
                                               const float* __restrict__ stats_in,
                                               const float* __restrict__ g,
                                               const float* __restrict__ be,
                                               const float* __restrict__ bias,
                                               u16* __restrict__ Y,
                                               float* __restrict__ stats, int N, int K) {
    __shared__ u16 As[2][8192];
    __shared__ u16 Ws[2][8192];
    __shared__ __align__(16) float bns[512];
    __shared__ __align__(16) float bnh[512];
    int tid = threadIdx.x;
    int wave = tid >> 6, lane = tid & 63;
    int wm = wave >> 1, wn = wave & 1;
    int bx, by;
    remap<2>(bx, by);
    int n0 = bx * 128, m0 = by * 128;
    int q = lane >> 4, l16 = lane & 15;
    f32x4 acc[4][4];
#pragma unroll
    for (int i = 0; i < 4; ++i)
#pragma unroll
        for (int j = 0; j < 4; ++j) acc[i][j] = {0.f, 0.f, 0.f, 0.f};
    int lr = lane >> 3, ch = lane & 7;
    size_t ldb = (size_t)K * 2;
    const char* actb = (const char*)Act + (size_t)m0 * ldb + ch * 16;
    const char* wb = (const char*)W + (size_t)n0 * ldb;
    uint4 rg[4];
#pragma unroll
    for (int i = 0; i < 4; ++i)
        rg[i] = *(const uint4*)(actb + (size_t)(wave * 32 + i * 8 + lr) * ldb);
    stage_tile(wb, ldb, Ws[0], wave, lane);
    // inline BN finalize (stats of previous layer -> scale/shift in LDS)
    const float inv = 1.0f / (float)MTOT;
    for (int k = tid; k < K; k += 256) {
        float mean = stats_in[k] * inv;
        float var = stats_in[K + k] * inv - mean * mean;
        float s = g[k] * rsqrtf(var + 1e-5f);
        bns[k] = s;
        bnh[k] = be[k] - mean * s;
    }
    __syncthreads();
    {
        f32x4 s0 = *(const f32x4*)&bns[ch * 8];
        f32x4 s1 = *(const f32x4*)&bns[ch * 8 + 4];
        f32x4 h0 = *(const f32x4*)&bnh[ch * 8];
        f32x4 h1 = *(const f32x4*)&bnh[ch * 8 + 4];
#pragma unroll
        for (int i = 0; i < 4; ++i) {
            int r = wave * 32 + i * 8 + lr;
            *(uint4*)&As[0][r * 64 + ((ch ^ swz8(r)) << 3)] = bn8v(rg[i], s0, s1, h0, h1);
        }
    }
    __syncthreads();
    int cur = 0;
    for (int kt = 64; kt < K; kt += 64) {
#pragma unroll
        for (int i = 0; i < 4; ++i)
            rg[i] = *(const uint4*)(actb + (size_t)(wave * 32 + i * 8 + lr) * ldb + kt * 2);
        stage_tile(wb + kt * 2, ldb, Ws[cur ^ 1], wave, lane);
        compute64(As[cur], Ws[cur], wm, wn, l16, q, acc);
        f32x4 s0 = *(const f32x4*)&bns[kt + ch * 8];
        f32x4 s1 = *(const f32x4*)&bns[kt + ch * 8 + 4];
        f32x4 h0 = *(const f32x4*)&bnh[kt + ch * 8];
        f32x4 h1 = *(const f32x4*)&bnh[kt + ch * 8 + 4];
#pragma unroll
        for (int i = 0; i < 4; ++i) {
            int r = wave * 32 + i * 8 + lr;
            *(uint4*)&As[cur ^ 1][r * 64 + ((ch ^ swz8(r)) << 3)] = bn8v(rg[i], s0, s1, h0, h1);
        }
        __syncthreads();
        cur ^= 1;
    }
    compute64(As[cur], Ws[cur], wm, wn, l16, q, acc);

    float bv[4];
#pragma unroll
    for (int ni = 0; ni < 4; ++ni)
        bv[ni] = bias[n0 + wn * 64 + ni * 16 + l16];
    float s1[4] = {0.f, 0.f, 0.f, 0.f}, s2[4] = {0.f, 0.f, 0.f, 0.f};
#pragma unroll
    for (int mi = 0; mi < 4; ++mi) {
#pragma unroll
        for (int r = 0; r < 4; ++r) {
            int m = m0 + wm * 64 + mi * 16 + q * 4 + r;
#pragma unroll
            for (int ni = 0; ni < 4; ++ni) {
                float v = acc[mi][ni][r] + bv[ni];
                Y[(size_t)m * N + (n0 + wn * 64 + ni * 16 + l16)] = f2b(v);
                s1[ni] += v;
                s2[ni] += v * v;
            }
        }
    }
#pragma unroll
    for (int ni = 0; ni < 4; ++ni) {
        float a = s1[ni], bq = s2[ni];
        a += __shfl_xor(a, 16); a += __shfl_xor(a, 32);
        bq += __shfl_xor(bq, 16); bq += __shfl_xor(bq, 32);
        if (q == 0) {
            int n = n0 + wn * 64 + ni * 16 + l16;
            atomicAdd(&stats[n], a);
            atomicAdd(&stats[N + n], bq);
        }
    }
}

// ---------------- merged low-res level GEMMs, x-transpose fused into A-staging ----------------
__global__ __launch_bounds__(256) void gemm_levels(const u16* __restrict__ wb1f,
                                                   const float* __restrict__ x2,
                                                   const float* __restrict__ x3,
                                                   const float* __restrict__ x4,
                                                   u16* __restrict__ G1,
                                                   u16* __restrict__ G2,
                                                   u16* __restrict__ G3) {
    __shared__ u16 As[2][8192];
    __shared__ u16 Ws[2][8192];
    int tid = threadIdx.x;
    int wave = tid >> 6, lane = tid & 63;
    int wm = wave >> 1, wn = wave & 1;
    int swz = xcd_swz(blockIdx.y * 4 + blockIdx.x, 672);
    int bx = swz & 3, by = swz >> 2;
    const float* X; u16* G; const u16* W;
    int mt, s2;
    if (by < 128)      { X = x2; G = G1; W = wb1f + 1 * 131072; mt = by;       s2 = 12; }
    else if (by < 160) { X = x3; G = G2; W = wb1f + 2 * 131072; mt = by - 128; s2 = 10; }
    else               { X = x4; G = G3; W = wb1f + 3 * 131072; mt = by - 160; s2 = 8; }
    int n0 = bx * 128, m0 = mt * 128;
    size_t plane = (size_t)1 << s2;
    int b = m0 >> s2;
    int pxbase = m0 & ((1 << s2) - 1);
    const float* xb0 = X + ((size_t)b * 256) * plane + pxbase;
    int q = lane >> 4, l16 = lane & 15;
    f32x4 acc[4][4];
#pragma unroll
    for (int i = 0; i < 4; ++i)
#pragma unroll
        for (int j = 0; j < 4; ++j) acc[i][j] = {0.f, 0.f, 0.f, 0.f};
    const char* wb = (const char*)W + (size_t)n0 * 512;

    uint4 rg[8];
    load_a(xb0, plane, tid, rg);
    stage_tile(wb, 512, Ws[0], wave, lane);
    write_a(rg, As[0], tid);
    __syncthreads();
    int cur = 0;
#pragma unroll
    for (int kt = 64; kt < 256; kt += 64) {
        load_a(xb0 + (size_t)kt * plane, plane, tid, rg);
        stage_tile(wb + kt * 2, 512, Ws[cur ^ 1], wave, lane);
        compute64(As[cur], Ws[cur], wm, wn, l16, q, acc);
        write_a(rg, As[cur ^ 1], tid);
        __syncthreads();
        cur ^= 1;
    }
    compute64(As[cur], Ws[cur], wm, wn, l16, q, acc);

#pragma unroll
    for (int mi = 0; mi < 4; ++mi)
#pragma unroll
        for (int r = 0; r < 4; ++r) {
            int m = m0 + wm * 64 + mi * 16 + q * 4 + r;
#pragma unroll
            for (int ni = 0; ni < 4; ++ni)
                G[(size_t)m * 512 + (n0 + wn * 64 + ni * 16 + l16)] = f2b(acc[mi][ni][r]);
        }
}

// ---------------- fused layer-1: x1 transpose GEMM + overlapped gathers + PEC + stats ----------------
__global__ __launch_bounds__(256) void gemm_f1x(const u16* __restrict__ W,
                                                const float* __restrict__ x1,
                                                const u16* __restrict__ G1,
                                                const u16* __restrict__ G2,
                                                const u16* __restrict__ G3,
                                                const float* __restrict__ pec,
                                                u16* __restrict__ Y,
                                                float* __restrict__ stats) {
    __shared__ u16 As[2][8192];
    __shared__ u16 Ws[2][8192];
    int tid = threadIdx.x;
    int wave = tid >> 6, lane = tid & 63;
    int wm = wave >> 1, wn = wave & 1;
    int bx, by;
    remap<4>(bx, by);
    int n0 = bx * 128, m0 = by * 128;
    int q = lane >> 4, l16 = lane & 15;
    f32x4 acc[4][4];
#pragma unroll
    for (int i = 0; i < 4; ++i)
#pragma unroll
        for (int j = 0; j < 4; ++j) acc[i][j] = {0.f, 0.f, 0.f, 0.f};
    int b = m0 >> 14;
    int iy = (m0 >> 7) & 127;
    const float* xb0 = x1 + ((size_t)b * 256) * 16384 + (size_t)iy * 128;
    const char* wb = (const char*)W + (size_t)n0 * 512;

    uint4 rg[8];
    load_a(xb0, 16384, tid, rg);
    stage_tile(wb, 512, Ws[0], wave, lane);
    write_a(rg, As[0], tid);
    __syncthreads();
    int cur = 0;
#pragma unroll
    for (int kt = 64; kt < 256; kt += 64) {
        load_a(xb0 + (size_t)kt * 16384, 16384, tid, rg);
        stage_tile(wb + kt * 2, 512, Ws[cur ^ 1], wave, lane);
        compute64(As[cur], Ws[cur], wm, wn, l16, q, acc);
        write_a(rg, As[cur ^ 1], tid);
        __syncthreads();
        cur ^= 1;
    }
    // cur == 1 here. Buffers [0] are dead: stage gathers into them via global_load_lds
    // BEFORE the final MFMA block so the HBM latency hides under compute.
    {
        const char* g1p = (const char*)(G1 + ((size_t)(b * 4096 + (iy >> 1) * 64)) * 512 + n0);
        const char* g2p = (const char*)(G2 + ((size_t)(b * 1024 + (iy >> 2) * 32)) * 512 + n0);
        const char* g3p = (const char*)(G3 + ((size_t)(b * 256  + (iy >> 3) * 16)) * 512 + n0);
        const char* ppp = (const char*)(pec + (size_t)((iy & 7) * 8) * 512 + n0);
        char* ga = (char*)&As[0][0];
        char* gw = (char*)&Ws[0][0];
#pragma unroll
        for (int it = 0; it < 4; ++it) {
            int u = it * 256 + tid;
            gload16(g1p + (size_t)(u >> 4) * 1024 + (u & 15) * 16, ga + it * 4096 + wave * 1024);
        }
#pragma unroll
        for (int it = 0; it < 2; ++it) {
            int u = it * 256 + tid;
            gload16(g2p + (size_t)(u >> 4) * 1024 + (u & 15) * 16, gw + it * 4096 + wave * 1024);
        }
        gload16(g3p + (size_t)(tid >> 4) * 1024 + (tid & 15) * 16, gw + 8192 + wave * 1024);
        gload16(ppp + (size_t)(tid >> 5) * 2048 + (tid & 31) * 16, gw + 12288 + wave * 1024);
    }
    compute64(As[1], Ws[1], wm, wn, l16, q, acc);
    __syncthreads();   // drains gather gloads

    // factored epilogue: g2 const over r; g3 const over r, depends on q>>1;
    // g1 shared by r-pairs; pec independent of mi.
    const u16* g1s = &As[0][0];                    // [64][128]
    const u16* g2s = &Ws[0][0];                    // [32][128]
    const u16* g3s = &Ws[0][0] + 4096;             // [16][128]
    const float* pecs = (const float*)(&Ws[0][0] + 6144);  // [8][128]
    int qh = q >> 1, q2 = q * 2, qp = (q & 1) * 4;
    float s1[4] = {0.f, 0.f, 0.f, 0.f}, s2[4] = {0.f, 0.f, 0.f, 0.f};
#pragma unroll
    for (int ni = 0; ni < 4; ++ni) {
        int nl = wn * 64 + ni * 16 + l16;
        float pe[4];
#pragma unroll
        for (int r = 0; r < 4; ++r) pe[r] = pecs[(qp + r) * 128 + nl];
#pragma unroll
        for (int mi = 0; mi < 4; ++mi) {
            float s23 = b2f(g2s[(wm * 16 + mi * 4 + q) * 128 + nl])
                      + b2f(g3s[(wm * 8 + mi * 2 + qh) * 128 + nl]);
            float sA = s23 + b2f(g1s[(wm * 32 + mi * 8 + q2) * 128 + nl]);
            float sB = s23 + b2f(g1s[(wm * 32 + mi * 8 + q2 + 1) * 128 + nl]);
#pragma unroll
            for (int r = 0; r < 4; ++r) {
                int ix = wm * 64 + mi * 16 + q * 4 + r;
                float v = acc[mi][ni][r] + (r < 2 ? sA : sB) + pe[r];
                Y[(size_t)(m0 + ix) * 512 + (n0 + nl)] = f2b(v);
                s1[ni] += v;
                s2[ni] += v * v;
            }
        }
    }
#pragma unroll
    for (int ni = 0; ni < 4; ++ni) {
        float a = s1[ni], bq = s2[ni];
        a += __shfl_xor(a, 16); a += __shfl_xor(a, 32);
        bq += __shfl_xor(bq, 16); bq += __shfl_xor(bq, 32);
        if (q == 0) {
            int n = n0 + wn * 64 + ni * 16 + l16;
            atomicAdd(&stats[n], a);
            atomicAdd(&stats[512 + n], bq);
        }
    }
}

// ---------------- final: inline BN3 finalize + ReLU + 256 -> 19 conv (grid-stride) ----------------
__global__ __launch_bounds__(256) void gemm4_out(const u16* __restrict__ Y3,
                                                 const float* __restrict__ w4,
                                                 const float* __restrict__ b4,
                                                 const float* __restrict__ stats3,
                                                 const float* __restrict__ g3,
                                                 const float* __restrict__ be3,
                                                 float* __restrict__ out) {
    __shared__ float w4s[19 * 256];
    int t = threadIdx.x;
    for (int i = t; i < 19 * 256; i += 256) w4s[i] = w4[i];
    __syncthreads();
    int mloc = t >> 4, l16 = t & 15;
    const float inv = 1.0f / (float)MTOT;
    float sc[16], sh[16];
#pragma unroll
    for (int j = 0; j < 16; ++j) {
        int c = l16 * 16 + j;
        float mean = stats3[c] * inv;
        float var = stats3[256 + c] * inv - mean * mean;
        float s = g3[c] * rsqrtf(var + 1e-5f);
        sc[j] = s;
        sh[j] = be3[c] - mean * s;
    }
    for (int mt = blockIdx.x; mt < 4096; mt += gridDim.x) {
        int m = mt * 16 + mloc;
        const uint4* yp = (const uint4*)((const char*)Y3 + (size_t)m * 512 + l16 * 32);
        uint4 v0 = yp[0], v1 = yp[1];
        uint32_t uu[8] = {v0.x, v0.y, v0.z, v0.w, v1.x, v1.y, v1.z, v1.w};
        float y[16];
#pragma unroll
        for (int p = 0; p < 8; ++p) {
            y[p * 2]     = __uint_as_float(uu[p] << 16);
            y[p * 2 + 1] = __uint_as_float(uu[p] & 0xffff0000u);
        }
#pragma unroll
        for (int j = 0; j < 16; ++j) y[j] = fmaxf(y[j] * sc[j] + sh[j], 0.f);
        float accv[19];
#pragma unroll
        for (int c = 0; c < 19; ++c) {
            const float* wr = &w4s[c * 256 + l16 * 16];
            float s = 0.f;
#pragma unroll
            for (int j = 0; j < 16; ++j) s += y[j] * wr[j];
            accv[c] = s;
        }
#pragma unroll
        for (int c = 0; c < 19; ++c) {
            float s = accv[c];
            s += __shfl_xor(s, 8, 16);
            s += __shfl_xor(s, 4, 16);
            s += __shfl_xor(s, 2, 16);
            s += __shfl_xor(s, 1, 16);
            accv[c] = s;
        }
        if (l16 == 0) {
            int b = m >> 14, l = m & 16383;
#pragma unroll
            for (int c = 0; c < 19; ++c)
                out[((size_t)b * 19 + c) * 16384 + l] = accv[c] + b4[c];
        }
    }
}

extern "C" void kernel_launch(void* const* d_in, const int* in_sizes, int n_in,
                              void* d_out, int out_size, void* d_ws, size_t ws_size,
                              hipStream_t stream) {
    const float* x1 = (const float*)d_in[0];
    const float* x2 = (const float*)d_in[1];
    const float* x3 = (const float*)d_in[2];
    const float* x4 = (const float*)d_in[3];
    const float* w1 = (const float*)d_in[4];
    const float* b1 = (const float*)d_in[5];
    const float* g1 = (const float*)d_in[6];
    const float* be1 = (const float*)d_in[7];
    const float* w2 = (const float*)d_in[8];
    const float* b2 = (const float*)d_in[9];
    const float* g2 = (const float*)d_in[10];
    const float* be2 = (const float*)d_in[11];
    const float* w3 = (const float*)d_in[12];
    const float* b3 = (const float*)d_in[13];
    const float* g3 = (const float*)d_in[14];
    const float* be3 = (const float*)d_in[15];
    const float* w4 = (const float*)d_in[16];
    const float* b4 = (const float*)d_in[17];

    char* ws = (char*)d_ws;
    u16* Y3  = (u16*)(ws + 0);            // [65536][256]
    u16* Y2  = (u16*)(ws + 33554432);     // [65536][256]
    u16* G1  = (u16*)(ws + 44564480);     // [16384][512]
    u16* G2  = (u16*)(ws + 61341696);     // [4096][512]
    u16* G3  = (u16*)(ws + 65536000);     // [1024][512]
    u16* Y1  = (u16*)(ws + 67108864);     // [65536][512]
    u16* wb1f = (u16*)(ws + 134217728);   // [4][512][256]
    u16* wb2 = (u16*)(ws + 135266304);    // [256][512]
    u16* wb3 = (u16*)(ws + 135528448);    // [256][256]
    float* pec = (float*)(ws + 135659520);// [64][512] f32
    float* stats = (float*)(ws + 135790592);

    prep<<<417, 512, 0, stream>>>(w1, b1, w2, w3, pec, wb1f, wb2, wb3, stats);

    gemm_levels<<<dim3(4, 168), 256, 0, stream>>>(wb1f, x2, x3, x4, G1, G2, G3);

    gemm_f1x<<<dim3(4, 512), 256, 0, stream>>>(wb1f, x1, G1, G2, G3, pec, Y1, stats);

    gemm_bn<<<dim3(2, 512), 256, 0, stream>>>(wb2, Y1, stats, g1, be1, b2, Y2,
                                              stats + 1024, 256, 512);

    gemm_bn<<<dim3(2, 512), 256, 0, stream>>>(wb3, Y2, stats + 1024, g2, be2, b3, Y3,
                                              stats + 2048, 256, 256);

    gemm4_out<<<512, 256, 0, stream>>>(Y3, w4, b4, stats + 2048, g3, be3, (float*)d_out);
}